// Round 2
// baseline (1365.161 us; speedup 1.0000x reference)
//
#include <hip/hip_runtime.h>
#include <hip/hip_bf16.h>

// Problem constants
#define D_    256
#define NH_   8
#define DH_   32
#define NQ_   900
#define BS_   8
#define NT_   7200      // NQ*BS tokens
#define TOT_  13294
#define MV_   106352    // TOT*BS value tokens
#define DFFN_ 1024

// ---------------------------------------------------------------------------
// Elementwise add (float4 vectorized): out = a + b
// ---------------------------------------------------------------------------
__global__ __launch_bounds__(256) void add_k(float* __restrict__ out,
                                             const float* __restrict__ a,
                                             const float* __restrict__ b,
                                             int n4) {
  int i = blockIdx.x * 256 + threadIdx.x;
  if (i >= n4) return;
  float4 va = reinterpret_cast<const float4*>(a)[i];
  float4 vb = reinterpret_cast<const float4*>(b)[i];
  float4 r;
  r.x = va.x + vb.x; r.y = va.y + vb.y; r.z = va.z + vb.z; r.w = va.w + vb.w;
  reinterpret_cast<float4*>(out)[i] = r;
}

// ---------------------------------------------------------------------------
// Tiled fp32 GEMM: C[M][N] = act(A[M][K] @ W[N][K]^T + bias[N] [+ res[M][N]])
// 64x64 tile, K-step 16, 256 threads, 4x4 micro-tile.
// Requires: K % 16 == 0, N % 64 == 0 (all our calls satisfy this). M guarded.
// ---------------------------------------------------------------------------
template <int ACT, bool RES, typename CT>
__global__ __launch_bounds__(256) void gemm_k(const float* __restrict__ A,
                                              const float* __restrict__ W,
                                              const float* __restrict__ bias,
                                              const float* __restrict__ res,
                                              CT* __restrict__ C,
                                              int M, int N, int K) {
  __shared__ float As[16][65];
  __shared__ float Bs[16][65];
  const int tid = threadIdx.x;
  const int tx = tid & 15, ty = tid >> 4;
  const int m0 = blockIdx.y * 64, n0 = blockIdx.x * 64;
  float acc[4][4] = {};

  const int r = tid >> 2;          // 0..63 (tile row for loads)
  const int kq = (tid & 3) * 4;    // 0,4,8,12

  for (int k0 = 0; k0 < K; k0 += 16) {
    // A tile
    float4 va = make_float4(0.f, 0.f, 0.f, 0.f);
    int gm = m0 + r;
    if (gm < M) va = *reinterpret_cast<const float4*>(&A[(size_t)gm * K + k0 + kq]);
    As[kq + 0][r] = va.x; As[kq + 1][r] = va.y; As[kq + 2][r] = va.z; As[kq + 3][r] = va.w;
    // B tile (weights, row = output col n, N%64==0 so no guard)
    float4 vb = *reinterpret_cast<const float4*>(&W[(size_t)(n0 + r) * K + k0 + kq]);
    Bs[kq + 0][r] = vb.x; Bs[kq + 1][r] = vb.y; Bs[kq + 2][r] = vb.z; Bs[kq + 3][r] = vb.w;
    __syncthreads();
#pragma unroll
    for (int k = 0; k < 16; ++k) {
      float a[4], b[4];
#pragma unroll
      for (int i = 0; i < 4; ++i) a[i] = As[k][ty * 4 + i];
#pragma unroll
      for (int j = 0; j < 4; ++j) b[j] = Bs[k][tx * 4 + j];
#pragma unroll
      for (int i = 0; i < 4; ++i)
#pragma unroll
        for (int j = 0; j < 4; ++j) acc[i][j] += a[i] * b[j];
    }
    __syncthreads();
  }

#pragma unroll
  for (int i = 0; i < 4; ++i) {
    int gm = m0 + ty * 4 + i;
    if (gm >= M) continue;
#pragma unroll
    for (int j = 0; j < 4; ++j) {
      int gn = n0 + tx * 4 + j;
      float c = acc[i][j] + bias[gn];
      if (RES) c += res[(size_t)gm * N + gn];
      if (ACT == 1) c = fmaxf(c, 0.f);
      C[(size_t)gm * N + gn] = (CT)c;
    }
  }
}

// ---------------------------------------------------------------------------
// Flash-style self-attention.
// QK buffer: [t=q*8+b][512] (cols 0:256 = Q as h*32+d, 256:512 = K)
// V buffer:  [t][256]
// O buffer:  [t][256]
// grid = (4 q-chunks, NH, BS); block = 256 threads, thread = one query row.
// ---------------------------------------------------------------------------
__global__ __launch_bounds__(256) void attn_k(const float* __restrict__ QK,
                                              const float* __restrict__ V,
                                              float* __restrict__ O) {
  const int chunk = blockIdx.x;
  const int h = blockIdx.y, b = blockIdx.z;
  const int tid = threadIdx.x;
  const int qi = chunk * 225 + tid;
  const bool act = (tid < 225) && (qi < NQ_);

  __shared__ float Ks[128][32];
  __shared__ float Vs[128][32];

  float q[32], accv[32];
  float m = -1e30f, l = 0.f;
  if (act) {
    const float* qp = &QK[((size_t)qi * BS_ + b) * 512 + h * 32];
#pragma unroll
    for (int d = 0; d < 32; ++d) { q[d] = qp[d]; accv[d] = 0.f; }
  }

  for (int j0 = 0; j0 < NQ_; j0 += 128) {
    const int cnt = min(128, NQ_ - j0);
    for (int e = tid; e < cnt * 32; e += 256) {
      int jj = e >> 5, d = e & 31;
      size_t t = (size_t)(j0 + jj) * BS_ + b;
      Ks[jj][d] = QK[t * 512 + 256 + h * 32 + d];
      Vs[jj][d] = V[t * 256 + h * 32 + d];
    }
    __syncthreads();
    if (act) {
      for (int jj = 0; jj < cnt; ++jj) {
        float s = 0.f;
#pragma unroll
        for (int d = 0; d < 32; ++d) s += q[d] * Ks[jj][d];
        s *= 0.17677669529663687f;  // 1/sqrt(32)
        float mn = fmaxf(m, s);
        float c = __expf(m - mn);
        float p = __expf(s - mn);
        l = l * c + p;
#pragma unroll
        for (int d = 0; d < 32; ++d) accv[d] = accv[d] * c + p * Vs[jj][d];
        m = mn;
      }
    }
    __syncthreads();
  }

  if (act) {
    float inv = 1.f / l;
    float* o = &O[((size_t)qi * BS_ + b) * 256 + h * 32];
#pragma unroll
    for (int d = 0; d < 32; ++d) o[d] = accv[d] * inv;
  }
}

// ---------------------------------------------------------------------------
// Softmax over 16 values per (token, head). aw layout: [t][h*16 + l*4 + p]
// ---------------------------------------------------------------------------
__global__ __launch_bounds__(256) void softmax16_k(float* __restrict__ aw) {
  int i = blockIdx.x * 256 + threadIdx.x;
  if (i >= NT_ * NH_) return;
  float* p = &aw[(size_t)(i >> 3) * 128 + (i & 7) * 16];
  float v[16], mx = -1e30f;
#pragma unroll
  for (int k = 0; k < 16; ++k) { v[k] = p[k]; mx = fmaxf(mx, v[k]); }
  float s = 0.f;
#pragma unroll
  for (int k = 0; k < 16; ++k) { v[k] = __expf(v[k] - mx); s += v[k]; }
  float inv = 1.f / s;
#pragma unroll
  for (int k = 0; k < 16; ++k) p[k] = v[k] * inv;
}

// ---------------------------------------------------------------------------
// Multi-scale deformable sampling.
// One block per token t=q*8+b. 256 threads = (h=tid>>5, d=tid&31).
// val: bf16 [s*8+b][h*32+d]; off: [t][lp*2+c]; aw: [t][lp]; ref: [t][l*2+c]
// out: [t][h*32+d]
// ---------------------------------------------------------------------------
__global__ __launch_bounds__(256) void deform_k(const __hip_bfloat16* __restrict__ val,
                                                const float* __restrict__ off,
                                                const float* __restrict__ aw,
                                                const float* __restrict__ ref,
                                                float* __restrict__ out) {
  const int t = blockIdx.x;
  const int b = t & 7;
  const int tid = threadIdx.x;
  const int h = tid >> 5, d = tid & 31;

  __shared__ float sx[128], sy[128], sw[128];

  const int LH[4] = {100, 50, 25, 13};
  const int LW[4] = {100, 50, 25, 13};
  const int LS[4] = {0, 10000, 12500, 13125};

  if (tid < 128) {
    int lp = tid;                 // (h*4+l)*4+p
    int l = (lp >> 2) & 3;
    float ox = off[(size_t)t * 256 + lp * 2 + 0];
    float oy = off[(size_t)t * 256 + lp * 2 + 1];
    float rx = ref[((size_t)t * 4 + l) * 2 + 0];
    float ry = ref[((size_t)t * 4 + l) * 2 + 1];
    sx[lp] = rx * (float)LW[l] + ox - 0.5f;
    sy[lp] = ry * (float)LH[l] + oy - 0.5f;
    sw[lp] = aw[(size_t)t * 128 + lp];
  }
  __syncthreads();

  float acc = 0.f;
#pragma unroll
  for (int l = 0; l < 4; ++l) {
    const int Hl = LH[l], Wl = LW[l], st = LS[l];
#pragma unroll
    for (int p = 0; p < 4; ++p) {
      int lp = (h * 4 + l) * 4 + p;
      float x = sx[lp], y = sy[lp], a = sw[lp];
      float xf = floorf(x), yf = floorf(y);
      int x0 = (int)xf, y0 = (int)yf;
      float wx1 = x - xf, wx0 = 1.f - wx1;
      float wy1 = y - yf, wy0 = 1.f - wy1;
      float s = 0.f;
#pragma unroll
      for (int cy = 0; cy < 2; ++cy) {
#pragma unroll
        for (int cx = 0; cx < 2; ++cx) {
          int xi = x0 + cx, yi = y0 + cy;
          if (xi < 0 || xi >= Wl || yi < 0 || yi >= Hl) continue;
          size_t idx = (size_t)(st + yi * Wl + xi) * 8 + b;
          float v = __bfloat162float(val[idx * 256 + h * 32 + d]);
          float w = (cx ? wx1 : wx0) * (cy ? wy1 : wy0);
          s += w * v;
        }
      }
      acc += a * s;
    }
  }
  out[(size_t)t * 256 + tid] = acc;
}

// ---------------------------------------------------------------------------
// LayerNorm over rows of 256. One wave per row, 4 rows per block.
// ---------------------------------------------------------------------------
__global__ __launch_bounds__(256) void ln_k(const float* __restrict__ z,
                                            const float* __restrict__ g,
                                            const float* __restrict__ be,
                                            float* __restrict__ out, int rows) {
  const int wv = threadIdx.x >> 6, lane = threadIdx.x & 63;
  const int row = blockIdx.x * 4 + wv;
  if (row >= rows) return;
  float4 v = *reinterpret_cast<const float4*>(&z[(size_t)row * 256 + lane * 4]);
  float s = v.x + v.y + v.z + v.w;
#pragma unroll
  for (int o = 32; o; o >>= 1) s += __shfl_xor(s, o);
  float mean = s * (1.f / 256.f);
  float dx = v.x - mean, dy = v.y - mean, dz = v.z - mean, dw = v.w - mean;
  float vs = dx * dx + dy * dy + dz * dz + dw * dw;
#pragma unroll
  for (int o = 32; o; o >>= 1) vs += __shfl_xor(vs, o);
  float rstd = rsqrtf(vs * (1.f / 256.f) + 1e-5f);
  float4 gg = *reinterpret_cast<const float4*>(&g[lane * 4]);
  float4 bb = *reinterpret_cast<const float4*>(&be[lane * 4]);
  float4 r;
  r.x = dx * rstd * gg.x + bb.x;
  r.y = dy * rstd * gg.y + bb.y;
  r.z = dz * rstd * gg.z + bb.z;
  r.w = dw * rstd * gg.w + bb.w;
  *reinterpret_cast<float4*>(&out[(size_t)row * 256 + lane * 4]) = r;
}

// ---------------------------------------------------------------------------
extern "C" void kernel_launch(void* const* d_in, const int* in_sizes, int n_in,
                              void* d_out, int out_size, void* d_ws, size_t ws_size,
                              hipStream_t stream) {
  const float* tgt    = (const float*)d_in[0];
  const float* pos    = (const float*)d_in[1];
  const float* refpts = (const float*)d_in[2];
  const float* memory = (const float*)d_in[3];
  const float* sa_in_w  = (const float*)d_in[6];
  const float* sa_in_b  = (const float*)d_in[7];
  const float* sa_out_w = (const float*)d_in[8];
  const float* sa_out_b = (const float*)d_in[9];
  const float* norm1_g = (const float*)d_in[10];
  const float* norm1_b = (const float*)d_in[11];
  const float* norm2_g = (const float*)d_in[12];
  const float* norm2_b = (const float*)d_in[13];
  const float* norm3_g = (const float*)d_in[14];
  const float* norm3_b = (const float*)d_in[15];
  const float* samp_w = (const float*)d_in[16];
  const float* samp_b = (const float*)d_in[17];
  const float* attw_w = (const float*)d_in[18];
  const float* attw_b = (const float*)d_in[19];
  const float* val_w  = (const float*)d_in[20];
  const float* val_b  = (const float*)d_in[21];
  const float* outp_w = (const float*)d_in[22];
  const float* outp_b = (const float*)d_in[23];
  const float* lin1_w = (const float*)d_in[24];
  const float* lin1_b = (const float*)d_in[25];
  const float* lin2_w = (const float*)d_in[26];
  const float* lin2_b = (const float*)d_in[27];
  float* out = (float*)d_out;

  // workspace layout (float offsets)
  float* wsf  = (float*)d_ws;
  float* bufA = wsf;                       // 1,843,200  (7200x256)
  float* bufB = wsf + 1843200;             // 3,686,400  (7200x512)
  float* bufB2 = bufB + 1843200;           // aw raw (7200x128) inside B
  float* bufC = wsf + 5529600;             // 1,843,200
  float* bufD = wsf + 7372800;             // 1,843,200
  void*  bufE = (void*)(wsf + 9216000);    // 54.5 MB: val bf16 / hid fp32
  __hip_bfloat16* valb = (__hip_bfloat16*)bufE;
  float* hid = (float*)bufE;

  const int MTILES = (NT_ + 63) / 64;      // 113

  // 1. xq = tgt + pos
  add_k<<<1800, 256, 0, stream>>>(bufA, tgt, pos, NT_ * 256 / 4);
  // 2. QK projection: (7200x256)@(512x256)^T -> bufB
  gemm_k<0, false, float><<<dim3(8, MTILES), 256, 0, stream>>>(
      bufA, sa_in_w, sa_in_b, nullptr, bufB, NT_, 512, 256);
  // 3. V projection (input = tgt): -> bufC
  gemm_k<0, false, float><<<dim3(4, MTILES), 256, 0, stream>>>(
      tgt, sa_in_w + 512 * 256, sa_in_b + 512, nullptr, bufC, NT_, 256, 256);
  // 4. self-attention -> bufA
  attn_k<<<dim3(4, NH_, BS_), 256, 0, stream>>>(bufB, bufC, bufA);
  // 5. out projection + residual(tgt) -> bufC
  gemm_k<0, true, float><<<dim3(4, MTILES), 256, 0, stream>>>(
      bufA, sa_out_w, sa_out_b, tgt, bufC, NT_, 256, 256);
  // 6. tgt1 = LN(bufC, norm2) -> bufD
  ln_k<<<1800, 256, 0, stream>>>(bufC, norm2_g, norm2_b, bufD, NT_);
  // 7. q2 = tgt1 + pos -> bufA
  add_k<<<1800, 256, 0, stream>>>(bufA, bufD, pos, NT_ * 256 / 4);
  // 8. sampling offsets -> bufB
  gemm_k<0, false, float><<<dim3(4, MTILES), 256, 0, stream>>>(
      bufA, samp_w, samp_b, nullptr, bufB, NT_, 256, 256);
  // 9. attention weights raw -> bufB2
  gemm_k<0, false, float><<<dim3(2, MTILES), 256, 0, stream>>>(
      bufA, attw_w, attw_b, nullptr, bufB2, NT_, 128, 256);
  // 10. softmax over 16
  softmax16_k<<<225, 256, 0, stream>>>(bufB2);
  // 11. value projection -> bf16
  gemm_k<0, false, __hip_bfloat16><<<dim3(4, (MV_ + 63) / 64), 256, 0, stream>>>(
      memory, val_w, val_b, nullptr, valb, MV_, 256, 256);
  // 12. deformable sampling -> bufA
  deform_k<<<NT_, 256, 0, stream>>>(valb, bufB, bufB2, refpts, bufA);
  // 13. output projection + residual(tgt1) -> bufC
  gemm_k<0, true, float><<<dim3(4, MTILES), 256, 0, stream>>>(
      bufA, outp_w, outp_b, bufD, bufC, NT_, 256, 256);
  // 14. tgt2 = LN(bufC, norm1) -> bufD
  ln_k<<<1800, 256, 0, stream>>>(bufC, norm1_g, norm1_b, bufD, NT_);
  // 15. FFN hidden (ReLU) -> hid
  gemm_k<1, false, float><<<dim3(16, MTILES), 256, 0, stream>>>(
      bufD, lin1_w, lin1_b, nullptr, hid, NT_, DFFN_, 256);
  // 16. FFN out + residual(tgt2) -> bufC
  gemm_k<0, true, float><<<dim3(4, MTILES), 256, 0, stream>>>(
      hid, lin2_w, lin2_b, bufD, bufC, NT_, 256, DFFN_);
  // 17. final LN -> out
  ln_k<<<1800, 256, 0, stream>>>(bufC, norm3_g, norm3_b, out, NT_);
}

// Round 3
// 576.834 us; speedup vs baseline: 2.3666x; 2.3666x over previous
//
#include <hip/hip_runtime.h>

#define D_    256
#define NH_   8
#define NQ_   900
#define BS_   8
#define NT_   7200
#define TOT_  13294
#define MV_   106352
#define DFFN_ 1024

typedef __attribute__((ext_vector_type(8))) short short8;
typedef __attribute__((ext_vector_type(4))) float f32x4;

__device__ __forceinline__ ushort f2bf(float f) {
  union { float f; unsigned u; } v; v.f = f;
  unsigned r = (v.u + 0x7FFF + ((v.u >> 16) & 1)) >> 16;
  return (ushort)r;
}
__device__ __forceinline__ float bf2f(ushort u) {
  union { unsigned u; float f; } v; v.u = ((unsigned)u) << 16;
  return v.f;
}
__device__ __forceinline__ void stv(float* p, float v) { *p = v; }
__device__ __forceinline__ void stv(ushort* p, float v) { *p = f2bf(v); }

#define GLOAD_LDS16(g, l)                                            \
  __builtin_amdgcn_global_load_lds(                                  \
      (const __attribute__((address_space(1))) void*)(g),            \
      (__attribute__((address_space(3))) void*)(l), 16, 0, 0)

// ---------------------------------------------------------------------------
// f32 -> bf16 conversion kernels (grid-stride, float4 in / ushort4 out)
// ---------------------------------------------------------------------------
__global__ __launch_bounds__(256) void cvt_k(ushort* __restrict__ o,
                                             const float* __restrict__ a, int n4) {
  for (int i = blockIdx.x * 256 + threadIdx.x; i < n4; i += gridDim.x * 256) {
    float4 v = reinterpret_cast<const float4*>(a)[i];
    ushort4 r; r.x = f2bf(v.x); r.y = f2bf(v.y); r.z = f2bf(v.z); r.w = f2bf(v.w);
    reinterpret_cast<ushort4*>(o)[i] = r;
  }
}

__global__ __launch_bounds__(256) void cvtadd_k(ushort* __restrict__ o,
                                                const float* __restrict__ a,
                                                const float* __restrict__ b, int n4) {
  for (int i = blockIdx.x * 256 + threadIdx.x; i < n4; i += gridDim.x * 256) {
    float4 va = reinterpret_cast<const float4*>(a)[i];
    float4 vb = reinterpret_cast<const float4*>(b)[i];
    ushort4 r; r.x = f2bf(va.x + vb.x); r.y = f2bf(va.y + vb.y);
    r.z = f2bf(va.z + vb.z); r.w = f2bf(va.w + vb.w);
    reinterpret_cast<ushort4*>(o)[i] = r;
  }
}

// All 8 weight matrices -> one bf16 arena (concatenated, fixed offsets).
__global__ __launch_bounds__(256) void cvtw_k(ushort* __restrict__ dst,
    const float* s0, const float* s1, const float* s2, const float* s3,
    const float* s4, const float* s5, const float* s6, const float* s7) {
  // cumulative float4 counts
  for (int i = blockIdx.x * 256 + threadIdx.x; i < 253952; i += gridDim.x * 256) {
    const float* src; int base;
    if      (i < 49152)  { src = s0; base = 0; }
    else if (i < 65536)  { src = s1; base = 49152; }
    else if (i < 81920)  { src = s2; base = 65536; }
    else if (i < 90112)  { src = s3; base = 81920; }
    else if (i < 106496) { src = s4; base = 90112; }
    else if (i < 122880) { src = s5; base = 106496; }
    else if (i < 188416) { src = s6; base = 122880; }
    else                 { src = s7; base = 188416; }
    float4 v = reinterpret_cast<const float4*>(src)[i - base];
    ushort4 r; r.x = f2bf(v.x); r.y = f2bf(v.y); r.z = f2bf(v.z); r.w = f2bf(v.w);
    reinterpret_cast<ushort4*>(dst)[i] = r;
  }
}

// ---------------------------------------------------------------------------
// bf16 MFMA GEMM (m97 structure): C[M][N] = A[M][K] @ W[N][K]^T + bias
// 128x128 tile, BK=32, 256 thr (4 waves, 2x2), 4x4 16x16x32 frags per wave.
// SCAT: 0 = row-major C (CT float|ushort), 1 = QK scatter, 2 = V scatter.
// ---------------------------------------------------------------------------
template <int SCAT, bool RES, bool RELU, typename CT>
__global__ __launch_bounds__(256) void gemm_bf(
    const ushort* __restrict__ A, const ushort* __restrict__ W,
    const float* __restrict__ bias, const float* __restrict__ res,
    CT* __restrict__ C, ushort* __restrict__ C2, int M, int N, int K) {
  __shared__ ushort Alds[128 * 32];
  __shared__ ushort Blds[128 * 32];
  const int tid = threadIdx.x;
  const int w = tid >> 6, l = tid & 63;
  const int lr = l & 15, lg = l >> 4;
  const int m0 = blockIdx.y * 128, n0 = blockIdx.x * 128;
  const int wr = (w >> 1) * 64, wc = (w & 1) * 64;
  f32x4 acc[4][4] = {};

  const int rs = w * 32 + (l >> 2);   // staging row (chunk c adds +16)
  const int kk = (l & 3) * 8;         // staging k offset (elements)

  for (int k0 = 0; k0 < K; k0 += 32) {
    __syncthreads();
#pragma unroll
    for (int c = 0; c < 2; ++c) {
      int r = rs + c * 16;
      GLOAD_LDS16(A + (size_t)(m0 + r) * K + k0 + kk,
                  &Alds[(w * 32 + c * 16) * 32]);
      GLOAD_LDS16(W + (size_t)(n0 + r) * K + k0 + kk,
                  &Blds[(w * 32 + c * 16) * 32]);
    }
    __syncthreads();
    short8 af[4], bf_[4];
#pragma unroll
    for (int mi = 0; mi < 4; ++mi)
      af[mi] = *reinterpret_cast<const short8*>(&Alds[(wr + mi * 16 + lr) * 32 + lg * 8]);
#pragma unroll
    for (int ni = 0; ni < 4; ++ni)
      bf_[ni] = *reinterpret_cast<const short8*>(&Blds[(wc + ni * 16 + lr) * 32 + lg * 8]);
#pragma unroll
    for (int mi = 0; mi < 4; ++mi)
#pragma unroll
      for (int ni = 0; ni < 4; ++ni)
        acc[mi][ni] = __builtin_amdgcn_mfma_f32_16x16x32_bf16(af[mi], bf_[ni], acc[mi][ni], 0, 0, 0);
  }

#pragma unroll
  for (int mi = 0; mi < 4; ++mi)
#pragma unroll
    for (int ni = 0; ni < 4; ++ni) {
      int gn = n0 + wc + ni * 16 + lr;
      float bv = bias[gn];
      f32x4 v = acc[mi][ni];
#pragma unroll
      for (int r = 0; r < 4; ++r) {
        int gm = m0 + wr + mi * 16 + lg * 4 + r;
        if (gm >= M) continue;
        float cv = v[r] + bv;
        if (RES) cv += res[(size_t)gm * N + gn];
        if (RELU) cv = fmaxf(cv, 0.f);
        if (SCAT == 0) {
          stv(&C[(size_t)gm * N + gn], cv);
        } else if (SCAT == 1) {
          int q = gm >> 3, b = gm & 7;
          if (gn < 256) {
            int h = gn >> 5, d = gn & 31;
            ((ushort*)C)[(((size_t)b * 8 + h) * 1024 + q) * 32 + d] = f2bf(cv);
          } else {
            int g2 = gn - 256, h = g2 >> 5, d = g2 & 31;
            C2[(((size_t)b * 8 + h) * 960 + q) * 32 + d] = f2bf(cv);
          }
        } else {
          int q = gm >> 3, b = gm & 7, h = gn >> 5, d = gn & 31;
          ((ushort*)C)[(((size_t)b * 8 + h) * 960 + q) * 32 + d] = f2bf(cv);
        }
      }
    }
}

// ---------------------------------------------------------------------------
// MFMA flash self-attention. Q:[64][1024][32] K,V:[64][960][32] bf16.
// Block: 4 waves x 32 q-rows; iterate 15 kv-tiles of 64.
// Swapped QK^T (S^T = mfma(K, Q)) -> lane-group softmax -> P->LDS -> PV.
// O: bf16 [7200][256] (t = q*8+b, col h*32+d).
// ---------------------------------------------------------------------------
__global__ __launch_bounds__(256) void attn_mfma(
    const ushort* __restrict__ Q, const ushort* __restrict__ Kt,
    const ushort* __restrict__ Vt, ushort* __restrict__ O) {
  const int qt = blockIdx.x, pr = blockIdx.y;
  const int b = pr >> 3, h = pr & 7;
  const int tid = threadIdx.x, w = tid >> 6, l = tid & 63;
  const int lr = l & 15, lg = l >> 4;
  const int qbase = qt * 128 + w * 32;
  const float SC = 0.17677669529663687f;

  __shared__ ushort Klds[64 * 32];   // [kv][dh], slot^=((kv>>1)&3)
  __shared__ ushort Vlds[32 * 64];   // [d][kv],  slot^=(d&7)
  __shared__ ushort Plds[4 * 32 * 64]; // per-wave [q][kv], slot^=(q&7)

  short8 qf[2];
#pragma unroll
  for (int nf = 0; nf < 2; ++nf) {
    int q = qbase + nf * 16 + lr;
    qf[nf] = *reinterpret_cast<const short8*>(&Q[((size_t)pr * 1024 + q) * 32 + lg * 8]);
  }
  f32x4 ot[2][2] = {};
  float mrow[2] = {-1e30f, -1e30f};
  float lsum[2] = {0.f, 0.f};

  for (int kt = 0; kt < 15; ++kt) {
    const int kv0 = kt * 64;
    __syncthreads();
    {
      int row = tid >> 2, s = tid & 3;
      short8 kv8 = *reinterpret_cast<const short8*>(
          &Kt[((size_t)pr * 960 + kv0 + row) * 32 + s * 8]);
      int s2 = s ^ ((row >> 1) & 3);
      *reinterpret_cast<short8*>(&Klds[row * 32 + s2 * 8]) = kv8;
      ushort tmp[8];
      *reinterpret_cast<short8*>(tmp) = *reinterpret_cast<const short8*>(
          &Vt[((size_t)pr * 960 + kv0 + row) * 32 + s * 8]);
      int slot = row >> 3;
#pragma unroll
      for (int j = 0; j < 8; ++j) {
        int d = s * 8 + j;
        Vlds[d * 64 + (slot ^ (d & 7)) * 8 + (row & 7)] = tmp[j];
      }
    }
    __syncthreads();

    // QK^T -> S^T frags (kv = mf*16 + lg*4 + r, q = nf*16 + lr)
    short8 kf[4];
#pragma unroll
    for (int mf = 0; mf < 4; ++mf) {
      int row = mf * 16 + lr;
      int s2 = lg ^ ((row >> 1) & 3);
      kf[mf] = *reinterpret_cast<const short8*>(&Klds[row * 32 + s2 * 8]);
    }
    f32x4 sf[4][2];
#pragma unroll
    for (int mf = 0; mf < 4; ++mf)
#pragma unroll
      for (int nf = 0; nf < 2; ++nf) {
        f32x4 z = {0.f, 0.f, 0.f, 0.f};
        sf[mf][nf] = __builtin_amdgcn_mfma_f32_16x16x32_bf16(kf[mf], qf[nf], z, 0, 0, 0);
      }

#pragma unroll
    for (int nf = 0; nf < 2; ++nf) {
      float tm = -1e30f;
#pragma unroll
      for (int mf = 0; mf < 4; ++mf)
#pragma unroll
        for (int r = 0; r < 4; ++r) {
          float s = sf[mf][nf][r] * SC;
          int kv = kv0 + mf * 16 + lg * 4 + r;
          if (kv >= NQ_) s = -1e30f;
          sf[mf][nf][r] = s;
          tm = fmaxf(tm, s);
        }
      tm = fmaxf(tm, __shfl_xor(tm, 16));
      tm = fmaxf(tm, __shfl_xor(tm, 32));
      float mnew = fmaxf(mrow[nf], tm);
      float c = __expf(mrow[nf] - mnew);
      mrow[nf] = mnew;
      float ps = 0.f;
      int q_local = nf * 16 + lr;
#pragma unroll
      for (int mf = 0; mf < 4; ++mf) {
        ushort4 pk;
        float p0 = __expf(sf[mf][nf][0] - mnew);
        float p1 = __expf(sf[mf][nf][1] - mnew);
        float p2 = __expf(sf[mf][nf][2] - mnew);
        float p3 = __expf(sf[mf][nf][3] - mnew);
        ps += p0 + p1 + p2 + p3;
        pk.x = f2bf(p0); pk.y = f2bf(p1); pk.z = f2bf(p2); pk.w = f2bf(p3);
        int kvl = mf * 16 + lg * 4;
        int s3 = (kvl >> 3) ^ (q_local & 7);
        *reinterpret_cast<ushort4*>(
            &Plds[w * 2048 + q_local * 64 + s3 * 8 + (kvl & 7)]) = pk;
      }
      lsum[nf] = lsum[nf] * c + ps;
#pragma unroll
      for (int mf = 0; mf < 2; ++mf)
#pragma unroll
        for (int r = 0; r < 4; ++r) ot[mf][nf][r] *= c;
    }

    // PV: out^T += V^T @ P^T
#pragma unroll
    for (int ks = 0; ks < 2; ++ks) {
      short8 va[2], pb[2];
#pragma unroll
      for (int mf = 0; mf < 2; ++mf) {
        int d = mf * 16 + lr;
        int s3 = (ks * 4 + lg) ^ (d & 7);
        va[mf] = *reinterpret_cast<const short8*>(&Vlds[d * 64 + s3 * 8]);
      }
#pragma unroll
      for (int nf = 0; nf < 2; ++nf) {
        int q_local = nf * 16 + lr;
        int s3 = (ks * 4 + lg) ^ (q_local & 7);
        pb[nf] = *reinterpret_cast<const short8*>(&Plds[w * 2048 + q_local * 64 + s3 * 8]);
      }
#pragma unroll
      for (int mf = 0; mf < 2; ++mf)
#pragma unroll
        for (int nf = 0; nf < 2; ++nf)
          ot[mf][nf] = __builtin_amdgcn_mfma_f32_16x16x32_bf16(va[mf], pb[nf], ot[mf][nf], 0, 0, 0);
    }
  }

#pragma unroll
  for (int nf = 0; nf < 2; ++nf) {
    float ls = lsum[nf];
    ls += __shfl_xor(ls, 16);
    ls += __shfl_xor(ls, 32);
    float inv = 1.f / ls;
    int q = qbase + nf * 16 + lr;
    if (q < NQ_) {
#pragma unroll
      for (int mf = 0; mf < 2; ++mf) {
        ushort4 pk;
        pk.x = f2bf(ot[mf][nf][0] * inv); pk.y = f2bf(ot[mf][nf][1] * inv);
        pk.z = f2bf(ot[mf][nf][2] * inv); pk.w = f2bf(ot[mf][nf][3] * inv);
        int d0 = mf * 16 + lg * 4;
        *reinterpret_cast<ushort4*>(&O[((size_t)q * 8 + b) * 256 + h * 32 + d0]) = pk;
      }
    }
  }
}

// ---------------------------------------------------------------------------
// Softmax over 16 per (token, head). aw: [t][h*16 + l*4 + p] f32
// ---------------------------------------------------------------------------
__global__ __launch_bounds__(256) void softmax16_k(float* __restrict__ aw) {
  int i = blockIdx.x * 256 + threadIdx.x;
  if (i >= NT_ * NH_) return;
  float* p = &aw[(size_t)(i >> 3) * 128 + (i & 7) * 16];
  float v[16], mx = -1e30f;
#pragma unroll
  for (int k = 0; k < 16; ++k) { v[k] = p[k]; mx = fmaxf(mx, v[k]); }
  float s = 0.f;
#pragma unroll
  for (int k = 0; k < 16; ++k) { v[k] = __expf(v[k] - mx); s += v[k]; }
  float inv = 1.f / s;
#pragma unroll
  for (int k = 0; k < 16; ++k) p[k] = v[k] * inv;
}

// ---------------------------------------------------------------------------
// Multi-scale deformable sampling (bf16 value, bf16 out).
// ---------------------------------------------------------------------------
__global__ __launch_bounds__(256) void deform_k(const ushort* __restrict__ val,
                                                const float* __restrict__ off,
                                                const float* __restrict__ aw,
                                                const float* __restrict__ ref,
                                                ushort* __restrict__ out) {
  const int t = blockIdx.x;
  const int b = t & 7;
  const int tid = threadIdx.x;
  const int h = tid >> 5, d = tid & 31;

  __shared__ float sx[128], sy[128], sw[128];
  const int LH[4] = {100, 50, 25, 13};
  const int LS[4] = {0, 10000, 12500, 13125};

  if (tid < 128) {
    int lp = tid;
    int lvl = (lp >> 2) & 3;
    float ox = off[(size_t)t * 256 + lp * 2 + 0];
    float oy = off[(size_t)t * 256 + lp * 2 + 1];
    float rx = ref[((size_t)t * 4 + lvl) * 2 + 0];
    float ry = ref[((size_t)t * 4 + lvl) * 2 + 1];
    sx[lp] = rx * (float)LH[lvl] + ox - 0.5f;
    sy[lp] = ry * (float)LH[lvl] + oy - 0.5f;
    sw[lp] = aw[(size_t)t * 128 + lp];
  }
  __syncthreads();

  float acc = 0.f;
#pragma unroll
  for (int lvl = 0; lvl < 4; ++lvl) {
    const int Hl = LH[lvl], Wl = LH[lvl], st = LS[lvl];
#pragma unroll
    for (int p = 0; p < 4; ++p) {
      int lp = (h * 4 + lvl) * 4 + p;
      float x = sx[lp], y = sy[lp], a = sw[lp];
      float xf = floorf(x), yf = floorf(y);
      int x0 = (int)xf, y0 = (int)yf;
      float wx1 = x - xf, wx0 = 1.f - wx1;
      float wy1 = y - yf, wy0 = 1.f - wy1;
      float s = 0.f;
#pragma unroll
      for (int cy = 0; cy < 2; ++cy)
#pragma unroll
        for (int cx = 0; cx < 2; ++cx) {
          int xi = x0 + cx, yi = y0 + cy;
          if (xi < 0 || xi >= Wl || yi < 0 || yi >= Hl) continue;
          size_t idx = (size_t)(st + yi * Wl + xi) * 8 + b;
          float v = bf2f(val[idx * 256 + h * 32 + d]);
          s += ((cx ? wx1 : wx0) * (cy ? wy1 : wy0)) * v;
        }
      acc += a * s;
    }
  }
  out[(size_t)t * 256 + tid] = f2bf(acc);
}

// ---------------------------------------------------------------------------
// LayerNorm rows of 256, one wave per row.
// ---------------------------------------------------------------------------
__global__ __launch_bounds__(256) void ln_k(const float* __restrict__ z,
                                            const float* __restrict__ g,
                                            const float* __restrict__ be,
                                            float* __restrict__ out, int rows) {
  const int wv = threadIdx.x >> 6, lane = threadIdx.x & 63;
  const int row = blockIdx.x * 4 + wv;
  if (row >= rows) return;
  float4 v = *reinterpret_cast<const float4*>(&z[(size_t)row * 256 + lane * 4]);
  float s = v.x + v.y + v.z + v.w;
#pragma unroll
  for (int o = 32; o; o >>= 1) s += __shfl_xor(s, o);
  float mean = s * (1.f / 256.f);
  float dx = v.x - mean, dy = v.y - mean, dz = v.z - mean, dw = v.w - mean;
  float vs = dx * dx + dy * dy + dz * dz + dw * dw;
#pragma unroll
  for (int o = 32; o; o >>= 1) vs += __shfl_xor(vs, o);
  float rstd = rsqrtf(vs * (1.f / 256.f) + 1e-5f);
  float4 gg = *reinterpret_cast<const float4*>(&g[lane * 4]);
  float4 bb = *reinterpret_cast<const float4*>(&be[lane * 4]);
  float4 r;
  r.x = dx * rstd * gg.x + bb.x;
  r.y = dy * rstd * gg.y + bb.y;
  r.z = dz * rstd * gg.z + bb.z;
  r.w = dw * rstd * gg.w + bb.w;
  *reinterpret_cast<float4*>(&out[(size_t)row * 256 + lane * 4]) = r;
}

// ---------------------------------------------------------------------------
extern "C" void kernel_launch(void* const* d_in, const int* in_sizes, int n_in,
                              void* d_out, int out_size, void* d_ws, size_t ws_size,
                              hipStream_t stream) {
  const float* tgt    = (const float*)d_in[0];
  const float* pos    = (const float*)d_in[1];
  const float* refpts = (const float*)d_in[2];
  const float* memory = (const float*)d_in[3];
  const float* sa_in_b  = (const float*)d_in[7];
  const float* sa_out_b = (const float*)d_in[9];
  const float* norm1_g = (const float*)d_in[10];
  const float* norm1_b = (const float*)d_in[11];
  const float* norm2_g = (const float*)d_in[12];
  const float* norm2_b = (const float*)d_in[13];
  const float* norm3_g = (const float*)d_in[14];
  const float* norm3_b = (const float*)d_in[15];
  const float* samp_b = (const float*)d_in[17];
  const float* attw_b = (const float*)d_in[19];
  const float* val_b  = (const float*)d_in[21];
  const float* outp_b = (const float*)d_in[23];
  const float* lin1_b = (const float*)d_in[25];
  const float* lin2_b = (const float*)d_in[27];
  float* out = (float*)d_out;

  char* ws = (char*)d_ws;
  // persistent
  ushort* wbf  = (ushort*)(ws + 0);              // 2,031,616 B bf16 weight arena
  ushort* valb = (ushort*)(ws + 2097152);        // 54,452,224 B (106352 x 256)
  char*   S    = ws + 56549376;                  // 27,262,976 B scratch union
  float*  bufC = (float*)(ws + 83812352);        // 7,372,800
  float*  bufD = (float*)(ws + 91185152);        // 7,372,800

  // weight arena element offsets
  ushort* sa_in_bf  = wbf + 0;
  ushort* sa_out_bf = wbf + 196608;
  ushort* samp_bf   = wbf + 262144;
  ushort* attw_bf   = wbf + 327680;
  ushort* val_bf    = wbf + 360448;
  ushort* outp_bf   = wbf + 425984;
  ushort* lin1_bf   = wbf + 491520;
  ushort* lin2_bf   = wbf + 753664;

  // scratch union: phase 1 = chunk buf; phase 2 = attention; phase 3 = deform/ffn
  ushort* chunkb = (ushort*)S;                       // 27,262,976 (53248 x 256)
  ushort* Qatt   = (ushort*)(S + 0);                 // 4,194,304
  ushort* Katt   = (ushort*)(S + 4194304);           // 3,932,160
  ushort* Vatt   = (ushort*)(S + 8126464);           // 3,932,160
  ushort* bf16A  = (ushort*)(S + 12058624);          // 3,735,552
  ushort* bf16T  = (ushort*)(S + 15794176);          // 3,735,552
  ushort* O_bf   = (ushort*)(S + 19529728);          // 3,735,552
  ushort* bf16Q2 = (ushort*)(S + 0);                 // 3,735,552
  float*  offs   = (float*)(S + 3735552);            // 7,372,800
  float*  awb    = (float*)(S + 11108352);           // 3,686,400
  ushort* dbuf   = (ushort*)(S + 14794752);          // 3,735,552 (deform out bf16)
  ushort* bf16D  = (ushort*)(S + 0);                 // 3,735,552
  ushort* hid    = (ushort*)(S + 3735552);           // 14,942,208 (7296 x 1024)

  const float* saw = (const float*)d_in[6];
  // 1. weights -> bf16
  cvtw_k<<<992, 256, 0, stream>>>(wbf, saw, (const float*)d_in[8],
      (const float*)d_in[16], (const float*)d_in[18], (const float*)d_in[20],
      (const float*)d_in[22], (const float*)d_in[24], (const float*)d_in[26]);

  // 2. value projection, chunked (memory -> bf16 chunk -> GEMM -> valb bf16)
  cvt_k<<<2048, 256, 0, stream>>>(chunkb, memory, 53248 * 64);
  gemm_bf<0, false, false, ushort><<<dim3(2, 416), 256, 0, stream>>>(
      chunkb, val_bf, val_b, nullptr, valb, nullptr, 53248, 256, 256);
  cvt_k<<<2048, 256, 0, stream>>>(chunkb, memory + (size_t)53248 * 256, 53104 * 64);
  gemm_bf<0, false, false, ushort><<<dim3(2, 415), 256, 0, stream>>>(
      chunkb, val_bf, val_b, nullptr, valb + (size_t)53248 * 256, nullptr, 53104, 256, 256);

  // 3. self-attention inputs
  cvtadd_k<<<1800, 256, 0, stream>>>(bf16A, tgt, pos, NT_ * 64);
  cvt_k<<<1800, 256, 0, stream>>>(bf16T, tgt, NT_ * 64);
  gemm_bf<1, false, false, ushort><<<dim3(4, 57), 256, 0, stream>>>(
      bf16A, sa_in_bf, sa_in_b, nullptr, Qatt, Katt, NT_, 512, 256);
  gemm_bf<2, false, false, ushort><<<dim3(2, 57), 256, 0, stream>>>(
      bf16T, sa_in_bf + 512 * 256, sa_in_b + 512, nullptr, Vatt, nullptr, NT_, 256, 256);

  // 4. attention
  attn_mfma<<<dim3(8, 64), 256, 0, stream>>>(Qatt, Katt, Vatt, O_bf);

  // 5. out projection + residual(tgt) -> bufC ; LN2 -> bufD (tgt1)
  gemm_bf<0, true, false, float><<<dim3(2, 57), 256, 0, stream>>>(
      O_bf, sa_out_bf, sa_out_b, tgt, bufC, nullptr, NT_, 256, 256);
  ln_k<<<1800, 256, 0, stream>>>(bufC, norm2_g, norm2_b, bufD, NT_);

  // 6. q2 = tgt1 + pos ; sampling offsets + attention weights
  cvtadd_k<<<1800, 256, 0, stream>>>(bf16Q2, bufD, pos, NT_ * 64);
  gemm_bf<0, false, false, float><<<dim3(2, 57), 256, 0, stream>>>(
      bf16Q2, samp_bf, samp_b, nullptr, offs, nullptr, NT_, 256, 256);
  gemm_bf<0, false, false, float><<<dim3(1, 57), 256, 0, stream>>>(
      bf16Q2, attw_bf, attw_b, nullptr, awb, nullptr, NT_, 128, 256);
  softmax16_k<<<225, 256, 0, stream>>>(awb);

  // 7. deformable sampling -> dbuf (bf16)
  deform_k<<<NT_, 256, 0, stream>>>(valb, offs, awb, refpts, dbuf);

  // 8. output projection + residual(tgt1) -> bufC ; LN1 -> bufD (tgt2)
  gemm_bf<0, true, false, float><<<dim3(2, 57), 256, 0, stream>>>(
      dbuf, outp_bf, outp_b, bufD, bufC, nullptr, NT_, 256, 256);
  ln_k<<<1800, 256, 0, stream>>>(bufC, norm1_g, norm1_b, bufD, NT_);

  // 9. FFN
  cvt_k<<<1800, 256, 0, stream>>>(bf16D, bufD, NT_ * 64);
  gemm_bf<0, false, true, ushort><<<dim3(8, 57), 256, 0, stream>>>(
      bf16D, lin1_bf, lin1_b, nullptr, hid, nullptr, NT_, 1024, 256);
  gemm_bf<0, true, false, float><<<dim3(2, 57), 256, 0, stream>>>(
      hid, lin2_bf, lin2_b, bufD, bufC, nullptr, NT_, 256, 1024);
  ln_k<<<1800, 256, 0, stream>>>(bufC, norm3_g, norm3_b, out, NT_);
}

// Round 6
// 504.981 us; speedup vs baseline: 2.7034x; 1.1423x over previous
//
#include <hip/hip_runtime.h>

#define NQ_   900
#define NT_   7200
#define TOT_  13294
#define MV_   106352

typedef __attribute__((ext_vector_type(8))) short short8;
typedef __attribute__((ext_vector_type(4))) float f32x4;

__device__ __forceinline__ ushort f2bf(float f) {
  union { float f; unsigned u; } v; v.f = f;
  unsigned r = (v.u + 0x7FFF + ((v.u >> 16) & 1)) >> 16;
  return (ushort)r;
}
__device__ __forceinline__ float bf2f(ushort u) {
  union { unsigned u; float f; } v; v.u = ((unsigned)u) << 16;
  return v.f;
}
__device__ __forceinline__ void stv(float* p, float v) { *p = v; }
__device__ __forceinline__ void stv(ushort* p, float v) { *p = f2bf(v); }

#define GLOAD_LDS16(g, l)                                            \
  __builtin_amdgcn_global_load_lds(                                  \
      (const __attribute__((address_space(1))) void*)(g),            \
      (__attribute__((address_space(3))) void*)(l), 16, 0, 0)

// ---------------------------------------------------------------------------
// All 8 weight matrices -> one bf16 arena. Order (rows x 256):
// sa_in 512 | sa_out 256 | samp 256 | attw 128 | val 256 | outp 256 |
// lin1 1024 | lin2 256(x1024)
// ---------------------------------------------------------------------------
__global__ __launch_bounds__(256) void cvtw_k(ushort* __restrict__ dst,
    const float* s0, const float* s1, const float* s2, const float* s3,
    const float* s4, const float* s5, const float* s6, const float* s7) {
  for (int i = blockIdx.x * 256 + threadIdx.x; i < 237568; i += gridDim.x * 256) {
    const float* src; int base;
    if      (i < 32768)  { src = s0; base = 0; }
    else if (i < 49152)  { src = s1; base = 32768; }
    else if (i < 65536)  { src = s2; base = 49152; }
    else if (i < 73728)  { src = s3; base = 65536; }
    else if (i < 90112)  { src = s4; base = 73728; }
    else if (i < 106496) { src = s5; base = 90112; }
    else if (i < 172032) { src = s6; base = 106496; }
    else                 { src = s7; base = 172032; }
    float4 v = reinterpret_cast<const float4*>(src)[i - base];
    ushort4 r; r.x = f2bf(v.x); r.y = f2bf(v.y); r.z = f2bf(v.z); r.w = f2bf(v.w);
    reinterpret_cast<ushort4*>(dst)[i] = r;
  }
}

// ---------------------------------------------------------------------------
// Unified bf16 MFMA GEMM. BM=128, BN in {128,256}, BK=32, BN*2 threads.
// C[M][N] = A[M][K] @ W[N][K]^T + bias
// AMODE: 0 = A bf16 (global_load_lds), 1 = A fp32 (reg-stage+cvt),
//        2 = A fp32 + A2 fp32 add (reg-stage+cvt)
// OMODE: 0 = CT rowmajor; 1 = CT rowmajor + res(fp32); 2 = CT rowmajor ReLU;
//        4 = QK scatter (C=Q pad1024, C2=K 960); 5 = V scatter (960);
//        6 = value b-major scatter; 7 = offs(f32 C)/awb(f32 C2) split at 256
// ---------------------------------------------------------------------------
template <int BN, int AMODE, int OMODE, typename CT>
__global__ __launch_bounds__(BN * 2) void g2(
    const void* __restrict__ Av, const float* __restrict__ A2,
    const ushort* __restrict__ W, const float* __restrict__ bias,
    const float* __restrict__ bias2, const float* __restrict__ res,
    CT* __restrict__ C, void* __restrict__ C2v, int M, int N, int K) {
  constexpr int T = BN * 2;
  constexpr int WC = BN / 64;
  constexpr int NA = (128 * 32) / (T * 8);
  __shared__ ushort Alds[128 * 32];
  __shared__ ushort Blds[BN * 32];
  const int tid = threadIdx.x;
  const int w = tid >> 6, l = tid & 63;
  const int lr = l & 15, lg = l >> 4;
  const int m0 = blockIdx.y * 128, n0 = blockIdx.x * BN;
  const int wr = (w / WC) * 64, wc = (w % WC) * 64;
  f32x4 acc[4][4] = {};

  const int srow = tid >> 2;        // rows covered per chunk = T/4
  const int scol = (tid & 3) * 8;

  for (int k0 = 0; k0 < K; k0 += 32) {
    __syncthreads();
    // B staging (always bf16 weights, 2 chunks)
#pragma unroll
    for (int c = 0; c < 2; ++c) {
      int r = n0 + c * (T / 4) + srow;
      GLOAD_LDS16(W + (size_t)r * K + k0 + scol, &Blds[(c * (T / 4) + w * 16) * 32]);
    }
    // A staging
    if constexpr (AMODE == 0) {
#pragma unroll
      for (int c = 0; c < NA; ++c) {
        int r = m0 + c * (T / 4) + srow;
        if (r >= M) r = M - 1;
        GLOAD_LDS16((const ushort*)Av + (size_t)r * K + k0 + scol,
                    &Alds[(c * (T / 4) + w * 16) * 32]);
      }
    } else {
#pragma unroll
      for (int c = 0; c < NA; ++c) {
        int row = c * (T / 4) + srow;
        int gr = m0 + row; if (gr >= M) gr = M - 1;
        const float* ap = (const float*)Av + (size_t)gr * K + k0 + scol;
        float4 v0 = *reinterpret_cast<const float4*>(ap);
        float4 v1 = *reinterpret_cast<const float4*>(ap + 4);
        if constexpr (AMODE == 2) {
          const float* pp = A2 + (size_t)gr * K + k0 + scol;
          float4 p0 = *reinterpret_cast<const float4*>(pp);
          float4 p1 = *reinterpret_cast<const float4*>(pp + 4);
          v0.x += p0.x; v0.y += p0.y; v0.z += p0.z; v0.w += p0.w;
          v1.x += p1.x; v1.y += p1.y; v1.z += p1.z; v1.w += p1.w;
        }
        ushort tmp[8] = {f2bf(v0.x), f2bf(v0.y), f2bf(v0.z), f2bf(v0.w),
                         f2bf(v1.x), f2bf(v1.y), f2bf(v1.z), f2bf(v1.w)};
        *reinterpret_cast<short8*>(&Alds[row * 32 + scol]) =
            *reinterpret_cast<short8*>(tmp);
      }
    }
    __syncthreads();

    short8 af[4], bfr[4];
#pragma unroll
    for (int mi = 0; mi < 4; ++mi)
      af[mi] = *reinterpret_cast<const short8*>(&Alds[(wr + mi * 16 + lr) * 32 + lg * 8]);
#pragma unroll
    for (int ni = 0; ni < 4; ++ni)
      bfr[ni] = *reinterpret_cast<const short8*>(&Blds[(wc + ni * 16 + lr) * 32 + lg * 8]);
#pragma unroll
    for (int mi = 0; mi < 4; ++mi)
#pragma unroll
      for (int ni = 0; ni < 4; ++ni)
        acc[mi][ni] = __builtin_amdgcn_mfma_f32_16x16x32_bf16(af[mi], bfr[ni], acc[mi][ni], 0, 0, 0);
  }

#pragma unroll
  for (int mi = 0; mi < 4; ++mi)
#pragma unroll
    for (int ni = 0; ni < 4; ++ni) {
      int gn = n0 + wc + ni * 16 + lr;
      float bv = (OMODE == 7) ? (gn < 256 ? bias[gn] : bias2[gn - 256]) : bias[gn];
      f32x4 v = acc[mi][ni];
#pragma unroll
      for (int r = 0; r < 4; ++r) {
        int gm = m0 + wr + mi * 16 + lg * 4 + r;
        if (gm >= M) continue;
        float cv = v[r] + bv;
        if constexpr (OMODE == 0) {
          stv(&C[(size_t)gm * N + gn], cv);
        } else if constexpr (OMODE == 1) {
          cv += res[(size_t)gm * N + gn];
          stv(&C[(size_t)gm * N + gn], cv);
        } else if constexpr (OMODE == 2) {
          cv = fmaxf(cv, 0.f);
          stv(&C[(size_t)gm * N + gn], cv);
        } else if constexpr (OMODE == 4) {
          int q = gm >> 3, b = gm & 7;
          if (gn < 256) {
            int h = gn >> 5, d = gn & 31;
            ((ushort*)C)[(((size_t)b * 8 + h) * 1024 + q) * 32 + d] = f2bf(cv);
          } else {
            int gg = gn - 256, h = gg >> 5, d = gg & 31;
            ((ushort*)C2v)[(((size_t)b * 8 + h) * 960 + q) * 32 + d] = f2bf(cv);
          }
        } else if constexpr (OMODE == 5) {
          int q = gm >> 3, b = gm & 7, h = gn >> 5, d = gn & 31;
          ((ushort*)C)[(((size_t)b * 8 + h) * 960 + q) * 32 + d] = f2bf(cv);
        } else if constexpr (OMODE == 6) {
          int s = gm >> 3, b = gm & 7;
          ((ushort*)C)[((size_t)b * TOT_ + s) * 256 + gn] = f2bf(cv);
        } else if constexpr (OMODE == 7) {
          if (gn < 256) ((float*)C)[(size_t)gm * 256 + gn] = cv;
          else          ((float*)C2v)[(size_t)gm * 128 + gn - 256] = cv;
        }
      }
    }
}

// ---------------------------------------------------------------------------
// MFMA flash self-attention (round-2-verified structure + setprio).
// ---------------------------------------------------------------------------
__global__ __launch_bounds__(256) void attn_mfma(
    const ushort* __restrict__ Q, const ushort* __restrict__ Kt,
    const ushort* __restrict__ Vt, ushort* __restrict__ O) {
  const int qt = blockIdx.x, pr = blockIdx.y;
  const int b = pr >> 3, h = pr & 7;
  const int tid = threadIdx.x, w = tid >> 6, l = tid & 63;
  const int lr = l & 15, lg = l >> 4;
  const int qbase = qt * 128 + w * 32;
  const float SC = 0.17677669529663687f;

  __shared__ ushort Klds[64 * 32];
  __shared__ ushort Vlds[32 * 64];
  __shared__ ushort Plds[4 * 32 * 64];

  short8 qf[2];
#pragma unroll
  for (int nf = 0; nf < 2; ++nf) {
    int q = qbase + nf * 16 + lr;
    qf[nf] = *reinterpret_cast<const short8*>(&Q[((size_t)pr * 1024 + q) * 32 + lg * 8]);
  }
  f32x4 ot[2][2] = {};
  float mrow[2] = {-1e30f, -1e30f};
  float lsum[2] = {0.f, 0.f};

  for (int kt = 0; kt < 15; ++kt) {
    const int kv0 = kt * 64;
    __syncthreads();
    {
      int row = tid >> 2, s = tid & 3;
      short8 kv8 = *reinterpret_cast<const short8*>(
          &Kt[((size_t)pr * 960 + kv0 + row) * 32 + s * 8]);
      int s2 = s ^ ((row >> 1) & 3);
      *reinterpret_cast<short8*>(&Klds[row * 32 + s2 * 8]) = kv8;
      ushort tmp[8];
      *reinterpret_cast<short8*>(tmp) = *reinterpret_cast<const short8*>(
          &Vt[((size_t)pr * 960 + kv0 + row) * 32 + s * 8]);
      int slot = row >> 3;
#pragma unroll
      for (int j = 0; j < 8; ++j) {
        int d = s * 8 + j;
        Vlds[d * 64 + (slot ^ (d & 7)) * 8 + (row & 7)] = tmp[j];
      }
    }
    __syncthreads();

    short8 kf[4];
#pragma unroll
    for (int mf = 0; mf < 4; ++mf) {
      int row = mf * 16 + lr;
      int s2 = lg ^ ((row >> 1) & 3);
      kf[mf] = *reinterpret_cast<const short8*>(&Klds[row * 32 + s2 * 8]);
    }
    f32x4 sf[4][2];
    __builtin_amdgcn_s_setprio(1);
#pragma unroll
    for (int mf = 0; mf < 4; ++mf)
#pragma unroll
      for (int nf = 0; nf < 2; ++nf) {
        f32x4 z = {0.f, 0.f, 0.f, 0.f};
        sf[mf][nf] = __builtin_amdgcn_mfma_f32_16x16x32_bf16(kf[mf], qf[nf], z, 0, 0, 0);
      }
    __builtin_amdgcn_s_setprio(0);

#pragma unroll
    for (int nf = 0; nf < 2; ++nf) {
      float tm = -1e30f;
#pragma unroll
      for (int mf = 0; mf < 4; ++mf)
#pragma unroll
        for (int r = 0; r < 4; ++r) {
          float s = sf[mf][nf][r] * SC;
          int kv = kv0 + mf * 16 + lg * 4 + r;
          if (kv >= NQ_) s = -1e30f;
          sf[mf][nf][r] = s;
          tm = fmaxf(tm, s);
        }
      tm = fmaxf(tm, __shfl_xor(tm, 16));
      tm = fmaxf(tm, __shfl_xor(tm, 32));
      float mnew = fmaxf(mrow[nf], tm);
      float c = __expf(mrow[nf] - mnew);
      mrow[nf] = mnew;
      float ps = 0.f;
      int q_local = nf * 16 + lr;
#pragma unroll
      for (int mf = 0; mf < 4; ++mf) {
        ushort4 pk;
        float p0 = __expf(sf[mf][nf][0] - mnew);
        float p1 = __expf(sf[mf][nf][1] - mnew);
        float p2 = __expf(sf[mf][nf][2] - mnew);
        float p3 = __expf(sf[mf][nf][3] - mnew);
        ps += p0 + p1 + p2 + p3;
        pk.x = f2bf(p0); pk.y = f2bf(p1); pk.z = f2bf(p2); pk.w = f2bf(p3);
        int kvl = mf * 16 + lg * 4;
        int s3 = (kvl >> 3) ^ (q_local & 7);
        *reinterpret_cast<ushort4*>(
            &Plds[w * 2048 + q_local * 64 + s3 * 8 + (kvl & 7)]) = pk;
      }
      lsum[nf] = lsum[nf] * c + ps;
#pragma unroll
      for (int mf = 0; mf < 2; ++mf)
#pragma unroll
        for (int r = 0; r < 4; ++r) ot[mf][nf][r] *= c;
    }

#pragma unroll
    for (int ks = 0; ks < 2; ++ks) {
      short8 va[2], pb[2];
#pragma unroll
      for (int mf = 0; mf < 2; ++mf) {
        int d = mf * 16 + lr;
        int s3 = (ks * 4 + lg) ^ (d & 7);
        va[mf] = *reinterpret_cast<const short8*>(&Vlds[d * 64 + s3 * 8]);
      }
#pragma unroll
      for (int nf = 0; nf < 2; ++nf) {
        int q_local = nf * 16 + lr;
        int s3 = (ks * 4 + lg) ^ (q_local & 7);
        pb[nf] = *reinterpret_cast<const short8*>(&Plds[w * 2048 + q_local * 64 + s3 * 8]);
      }
      __builtin_amdgcn_s_setprio(1);
#pragma unroll
      for (int mf = 0; mf < 2; ++mf)
#pragma unroll
        for (int nf = 0; nf < 2; ++nf)
          ot[mf][nf] = __builtin_amdgcn_mfma_f32_16x16x32_bf16(va[mf], pb[nf], ot[mf][nf], 0, 0, 0);
      __builtin_amdgcn_s_setprio(0);
    }
  }

#pragma unroll
  for (int nf = 0; nf < 2; ++nf) {
    float ls = lsum[nf];
    ls += __shfl_xor(ls, 16);
    ls += __shfl_xor(ls, 32);
    float inv = 1.f / ls;
    int q = qbase + nf * 16 + lr;
    if (q < NQ_) {
#pragma unroll
      for (int mf = 0; mf < 2; ++mf) {
        ushort4 pk;
        pk.x = f2bf(ot[mf][nf][0] * inv); pk.y = f2bf(ot[mf][nf][1] * inv);
        pk.z = f2bf(ot[mf][nf][2] * inv); pk.w = f2bf(ot[mf][nf][3] * inv);
        int d0 = mf * 16 + lg * 4;
        *reinterpret_cast<ushort4*>(&O[((size_t)q * 8 + b) * 256 + h * 32 + d0]) = pk;
      }
    }
  }
}

// ---------------------------------------------------------------------------
// Multi-scale deformable sampling: 4 tokens/block, thread = (token, h, d/4).
// val: bf16 b-major [b][spatial][256]. Includes the 16-wide softmax on aw.
// ---------------------------------------------------------------------------
__global__ __launch_bounds__(256) void deform_k(const ushort* __restrict__ val,
                                                const float* __restrict__ off,
                                                const float* __restrict__ awraw,
                                                const float* __restrict__ ref,
                                                ushort* __restrict__ out) {
  const int t0 = blockIdx.x * 4;
  const int tid = threadIdx.x;
  __shared__ float sx[4][128], sy[4][128], sw[4][128];
  const int LH[4] = {100, 50, 25, 13};
  const int LS[4] = {0, 10000, 12500, 13125};

  for (int e = tid; e < 512; e += 256) {
    int tt = e >> 7, lp = e & 127;
    int t = t0 + tt;
    int lvl = (lp >> 2) & 3;
    float ox = off[(size_t)t * 256 + lp * 2 + 0];
    float oy = off[(size_t)t * 256 + lp * 2 + 1];
    float rx = ref[((size_t)t * 4 + lvl) * 2 + 0];
    float ry = ref[((size_t)t * 4 + lvl) * 2 + 1];
    sx[tt][lp] = rx * (float)LH[lvl] + ox - 0.5f;
    sy[tt][lp] = ry * (float)LH[lvl] + oy - 0.5f;
    sw[tt][lp] = awraw[(size_t)t * 128 + lp];
  }
  __syncthreads();
  if (tid < 32) {
    int tt = tid >> 3, h = tid & 7;
    float* p = &sw[tt][h * 16];
    float mx = -1e30f;
#pragma unroll
    for (int k = 0; k < 16; ++k) mx = fmaxf(mx, p[k]);
    float v[16], s = 0.f;
#pragma unroll
    for (int k = 0; k < 16; ++k) { v[k] = __expf(p[k] - mx); s += v[k]; }
    float inv = 1.f / s;
#pragma unroll
    for (int k = 0; k < 16; ++k) p[k] = v[k] * inv;
  }
  __syncthreads();

  const int tt = tid >> 6, u = tid & 63;
  const int h = u >> 3, d0 = (u & 7) * 4;
  const int t = t0 + tt, b = t & 7;
  float a0 = 0.f, a1 = 0.f, a2 = 0.f, a3 = 0.f;

#pragma unroll
  for (int lvl = 0; lvl < 4; ++lvl) {
    const int Hl = LH[lvl], st = LS[lvl];
#pragma unroll
    for (int p = 0; p < 4; ++p) {
      int lp = (h * 4 + lvl) * 4 + p;
      float x = sx[tt][lp], y = sy[tt][lp], a = sw[tt][lp];
      float xf = floorf(x), yf = floorf(y);
      int x0 = (int)xf, y0 = (int)yf;
      float wx1 = x - xf, wx0 = 1.f - wx1;
      float wy1 = y - yf, wy0 = 1.f - wy1;
      float s0 = 0.f, s1 = 0.f, s2 = 0.f, s3 = 0.f;
#pragma unroll
      for (int cy = 0; cy < 2; ++cy)
#pragma unroll
        for (int cx = 0; cx < 2; ++cx) {
          int xi = x0 + cx, yi = y0 + cy;
          if (xi < 0 || xi >= Hl || yi < 0 || yi >= Hl) continue;
          ushort4 v4 = *reinterpret_cast<const ushort4*>(
              &val[((size_t)b * TOT_ + st + yi * Hl + xi) * 256 + h * 32 + d0]);
          float wgt = (cx ? wx1 : wx0) * (cy ? wy1 : wy0);
          s0 += wgt * bf2f(v4.x); s1 += wgt * bf2f(v4.y);
          s2 += wgt * bf2f(v4.z); s3 += wgt * bf2f(v4.w);
        }
      a0 += a * s0; a1 += a * s1; a2 += a * s2; a3 += a * s3;
    }
  }
  ushort4 o4; o4.x = f2bf(a0); o4.y = f2bf(a1); o4.z = f2bf(a2); o4.w = f2bf(a3);
  *reinterpret_cast<ushort4*>(&out[(size_t)t * 256 + h * 32 + d0]) = o4;
}

// ---------------------------------------------------------------------------
// LayerNorm rows of 256, one wave per row.
// ---------------------------------------------------------------------------
__global__ __launch_bounds__(256) void ln_k(const float* __restrict__ z,
                                            const float* __restrict__ g,
                                            const float* __restrict__ be,
                                            float* __restrict__ out, int rows) {
  const int wv = threadIdx.x >> 6, lane = threadIdx.x & 63;
  const int row = blockIdx.x * 4 + wv;
  if (row >= rows) return;
  float4 v = *reinterpret_cast<const float4*>(&z[(size_t)row * 256 + lane * 4]);
  float s = v.x + v.y + v.z + v.w;
#pragma unroll
  for (int o = 32; o; o >>= 1) s += __shfl_xor(s, o);
  float mean = s * (1.f / 256.f);
  float dx = v.x - mean, dy = v.y - mean, dz = v.z - mean, dw = v.w - mean;
  float vs = dx * dx + dy * dy + dz * dz + dw * dw;
#pragma unroll
  for (int o = 32; o; o >>= 1) vs += __shfl_xor(vs, o);
  float rstd = rsqrtf(vs * (1.f / 256.f) + 1e-5f);
  float4 gg = *reinterpret_cast<const float4*>(&g[lane * 4]);
  float4 bb = *reinterpret_cast<const float4*>(&be[lane * 4]);
  float4 r;
  r.x = dx * rstd * gg.x + bb.x;
  r.y = dy * rstd * gg.y + bb.y;
  r.z = dz * rstd * gg.z + bb.z;
  r.w = dw * rstd * gg.w + bb.w;
  *reinterpret_cast<float4*>(&out[(size_t)row * 256 + lane * 4]) = r;
}

// ---------------------------------------------------------------------------
extern "C" void kernel_launch(void* const* d_in, const int* in_sizes, int n_in,
                              void* d_out, int out_size, void* d_ws, size_t ws_size,
                              hipStream_t stream) {
  const float* tgt    = (const float*)d_in[0];
  const float* pos    = (const float*)d_in[1];
  const float* refpts = (const float*)d_in[2];
  const float* memory = (const float*)d_in[3];
  const float* sa_in_b  = (const float*)d_in[7];
  const float* sa_out_b = (const float*)d_in[9];
  const float* norm1_g = (const float*)d_in[10];
  const float* norm1_b = (const float*)d_in[11];
  const float* norm2_g = (const float*)d_in[12];
  const float* norm2_b = (const float*)d_in[13];
  const float* norm3_g = (const float*)d_in[14];
  const float* norm3_b = (const float*)d_in[15];
  const float* samp_b = (const float*)d_in[17];
  const float* attw_b = (const float*)d_in[19];
  const float* val_b  = (const float*)d_in[21];
  const float* outp_b = (const float*)d_in[23];
  const float* lin1_b = (const float*)d_in[25];
  const float* lin2_b = (const float*)d_in[27];
  float* out = (float*)d_out;

  char* ws = (char*)d_ws;
  ushort* wbf  = (ushort*)(ws + 0);            // 1,900,544 B bf16 weight arena
  ushort* valb = (ushort*)(ws + 2097152);      // 54,449,152 B [b][13294][256]
  char*   S    = ws + 56549376;                // 27,262,976 B scratch union
  float*  bufC = (float*)(ws + 83812352);      // 7,372,800
  float*  bufD = (float*)(ws + 91185152);      // 7,372,800

  // weight arena element offsets (x256 cols)
  ushort* sa_in_bf  = wbf + 0;        // 512 rows
  ushort* sa_out_bf = wbf + 131072;   // 256
  ushort* sampw_bf  = wbf + 196608;   // 256 + 128 (attw contiguous -> 384)
  ushort* val_bf    = wbf + 294912;   // 256
  ushort* outp_bf   = wbf + 360448;   // 256
  ushort* lin1_bf   = wbf + 425984;   // 1024
  ushort* lin2_bf   = wbf + 688128;   // 256 x 1024

  // scratch union
  ushort* Qatt = (ushort*)(S + 0);         // 4,194,304
  ushort* Katt = (ushort*)(S + 4194304);   // 3,932,160
  ushort* Vatt = (ushort*)(S + 8126464);   // 3,932,160
  ushort* O_bf = (ushort*)(S + 12058624);  // 3,686,400
  float*  offs = (float*)(S + 0);          // 7,372,800  (after attn dead)
  float*  awb  = (float*)(S + 7372800);    // 3,686,400
  ushort* dbuf = (ushort*)(S + 11059200);  // 3,686,400
  ushort* hid  = (ushort*)(S + 0);         // 14,745,600 (after deform dead)

  // 1. weights -> bf16 arena
  cvtw_k<<<928, 256, 0, stream>>>(wbf, (const float*)d_in[6], (const float*)d_in[8],
      (const float*)d_in[16], (const float*)d_in[18], (const float*)d_in[20],
      (const float*)d_in[22], (const float*)d_in[24], (const float*)d_in[26]);

  // 2. value projection straight off fp32 memory -> valb (b-major bf16)
  g2<256, 1, 6, ushort><<<dim3(1, 831), 512, 0, stream>>>(
      memory, nullptr, val_bf, val_b, nullptr, nullptr, valb, nullptr, MV_, 256, 256);

  // 3. QK projection (A = tgt + pos) and V projection (A = tgt)
  g2<256, 2, 4, ushort><<<dim3(2, 57), 512, 0, stream>>>(
      tgt, pos, sa_in_bf, sa_in_b, nullptr, nullptr, Qatt, Katt, NT_, 512, 256);
  g2<128, 1, 5, ushort><<<dim3(2, 57), 256, 0, stream>>>(
      tgt, nullptr, sa_in_bf + 512 * 256, sa_in_b + 512, nullptr, nullptr,
      Vatt, nullptr, NT_, 256, 256);

  // 4. attention
  attn_mfma<<<dim3(8, 64), 256, 0, stream>>>(Qatt, Katt, Vatt, O_bf);

  // 5. out projection + residual(tgt) -> bufC ; LN2 -> bufD (tgt1)
  g2<128, 0, 1, float><<<dim3(2, 57), 256, 0, stream>>>(
      O_bf, nullptr, sa_out_bf, sa_out_b, nullptr, tgt, bufC, nullptr, NT_, 256, 256);
  ln_k<<<1800, 256, 0, stream>>>(bufC, norm2_g, norm2_b, bufD, NT_);

  // 6. fused offs+attw GEMM (A = tgt1 + pos, N=384 combined weights)
  g2<128, 2, 7, float><<<dim3(3, 57), 256, 0, stream>>>(
      bufD, pos, sampw_bf, samp_b, attw_b, nullptr, offs, awb, NT_, 384, 256);

  // 7. deformable sampling (includes aw softmax) -> dbuf bf16
  deform_k<<<1800, 256, 0, stream>>>(valb, offs, awb, refpts, dbuf);

  // 8. output projection + residual(tgt1) -> bufC ; LN1 -> bufD (tgt2)
  g2<128, 0, 1, float><<<dim3(2, 57), 256, 0, stream>>>(
      dbuf, nullptr, outp_bf, outp_b, nullptr, bufD, bufC, nullptr, NT_, 256, 256);
  ln_k<<<1800, 256, 0, stream>>>(bufC, norm1_g, norm1_b, bufD, NT_);

  // 9. FFN: lin1 (fp32 A, ReLU, bf16 out) ; lin2 (+res) ; LN3 -> out
  g2<256, 1, 2, ushort><<<dim3(4, 57), 512, 0, stream>>>(
      bufD, nullptr, lin1_bf, lin1_b, nullptr, nullptr, hid, nullptr, NT_, 1024, 256);
  g2<128, 0, 1, float><<<dim3(2, 57), 256, 0, stream>>>(
      hid, nullptr, lin2_bf, lin2_b, nullptr, bufD, bufC, nullptr, NT_, 256, 1024);
  ln_k<<<1800, 256, 0, stream>>>(bufC, norm3_g, norm3_b, out, NT_);
}

// Round 10
// 504.204 us; speedup vs baseline: 2.7076x; 1.0015x over previous
//
#include <hip/hip_runtime.h>

#define NQ_   900
#define NT_   7200
#define TOT_  13294
#define MV_   106352

typedef __attribute__((ext_vector_type(8))) short short8;
typedef __attribute__((ext_vector_type(4))) float f32x4;

__device__ __forceinline__ ushort f2bf(float f) {
  union { float f; unsigned u; } v; v.f = f;
  unsigned r = (v.u + 0x7FFF + ((v.u >> 16) & 1)) >> 16;
  return (ushort)r;
}
__device__ __forceinline__ float bf2f(ushort u) {
  union { unsigned u; float f; } v; v.u = ((unsigned)u) << 16;
  return v.f;
}
__device__ __forceinline__ void stv(float* p, float v) { *p = v; }
__device__ __forceinline__ void stv(ushort* p, float v) { *p = f2bf(v); }

#define GLOAD_LDS16(g, l)                                            \
  __builtin_amdgcn_global_load_lds(                                  \
      (const __attribute__((address_space(1))) void*)(g),            \
      (__attribute__((address_space(3))) void*)(l), 16, 0, 0)

// ---------------------------------------------------------------------------
// All 8 weight matrices -> one bf16 arena. Order (rows x 256):
// sa_in 512 | sa_out 256 | samp 256 | attw 128 | val 256 | outp 256 |
// lin1 1024 | lin2 256(x1024)
// ---------------------------------------------------------------------------
__global__ __launch_bounds__(256) void cvtw_k(ushort* __restrict__ dst,
    const float* s0, const float* s1, const float* s2, const float* s3,
    const float* s4, const float* s5, const float* s6, const float* s7) {
  for (int i = blockIdx.x * 256 + threadIdx.x; i < 237568; i += gridDim.x * 256) {
    const float* src; int base;
    if      (i < 32768)  { src = s0; base = 0; }
    else if (i < 49152)  { src = s1; base = 32768; }
    else if (i < 65536)  { src = s2; base = 49152; }
    else if (i < 73728)  { src = s3; base = 65536; }
    else if (i < 90112)  { src = s4; base = 73728; }
    else if (i < 106496) { src = s5; base = 90112; }
    else if (i < 172032) { src = s6; base = 106496; }
    else                 { src = s7; base = 172032; }
    float4 v = reinterpret_cast<const float4*>(src)[i - base];
    ushort4 r; r.x = f2bf(v.x); r.y = f2bf(v.y); r.z = f2bf(v.z); r.w = f2bf(v.w);
    reinterpret_cast<ushort4*>(dst)[i] = r;
  }
}

// ---------------------------------------------------------------------------
// Unified bf16 MFMA GEMM. BM=128, BN in {128,256}, BK=32, BN*2 threads.
// AMODE: 0 = A bf16 (global_load_lds), 1 = A fp32 reg-stage+cvt (prefetched),
//        2 = A fp32 + A2 fp32 add (prefetched), 3 = A fp32 s-major rows
//            (row = gr*8 + blockIdx.z, prefetched)
// OMODE: 0 rowmajor; 1 rowmajor+res; 2 rowmajor ReLU; 4 QK scatter;
//        5 V scatter; 7 offs/awb split at 256; 8 b-major value write (z=b)
// ---------------------------------------------------------------------------
template <int BN, int AMODE, int OMODE, typename CT>
__global__ __launch_bounds__(BN * 2) void g2(
    const void* __restrict__ Av, const float* __restrict__ A2,
    const ushort* __restrict__ W, const float* __restrict__ bias,
    const float* __restrict__ bias2, const float* __restrict__ res,
    CT* __restrict__ C, void* __restrict__ C2v, int M, int N, int K) {
  constexpr int T = BN * 2;
  constexpr int WC = BN / 64;
  constexpr int NA = (128 * 32) / (T * 8);
  __shared__ ushort Alds[128 * 32];
  __shared__ ushort Blds[BN * 32];
  const int tid = threadIdx.x;
  const int w = tid >> 6, l = tid & 63;
  const int lr = l & 15, lg = l >> 4;
  const int m0 = blockIdx.y * 128, n0 = blockIdx.x * BN;
  const int bz = blockIdx.z;
  const int wr = (w / WC) * 64, wc = (w % WC) * 64;
  f32x4 acc[4][4] = {};

  const int srow = tid >> 2;        // rows covered per chunk = T/4
  const int scol = (tid & 3) * 8;

  // A prefetch registers (reg-staged modes)
  float4 pa0[NA], pa1[NA], pb0[NA], pb1[NA];

  auto loadA = [&](int k0) {
#pragma unroll
    for (int c = 0; c < NA; ++c) {
      int gr = m0 + c * (T / 4) + srow;
      if (gr >= M) gr = M - 1;
      size_t arow = (AMODE == 3) ? ((size_t)gr * 8 + bz) : (size_t)gr;
      const float* ap = (const float*)Av + arow * K + k0 + scol;
      pa0[c] = *reinterpret_cast<const float4*>(ap);
      pa1[c] = *reinterpret_cast<const float4*>(ap + 4);
      if constexpr (AMODE == 2) {
        const float* pp = A2 + (size_t)gr * K + k0 + scol;
        pb0[c] = *reinterpret_cast<const float4*>(pp);
        pb1[c] = *reinterpret_cast<const float4*>(pp + 4);
      }
    }
  };

  if constexpr (AMODE != 0) loadA(0);

  for (int k0 = 0; k0 < K; k0 += 32) {
    __syncthreads();
    // B staging (bf16 weights via global_load_lds, 2 chunks)
#pragma unroll
    for (int c = 0; c < 2; ++c) {
      int r = n0 + c * (T / 4) + srow;
      GLOAD_LDS16(W + (size_t)r * K + k0 + scol, &Blds[(c * (T / 4) + w * 16) * 32]);
    }
    // A staging
    if constexpr (AMODE == 0) {
#pragma unroll
      for (int c = 0; c < NA; ++c) {
        int r = m0 + c * (T / 4) + srow;
        if (r >= M) r = M - 1;
        GLOAD_LDS16((const ushort*)Av + (size_t)r * K + k0 + scol,
                    &Alds[(c * (T / 4) + w * 16) * 32]);
      }
    } else {
#pragma unroll
      for (int c = 0; c < NA; ++c) {
        int row = c * (T / 4) + srow;
        float4 v0 = pa0[c], v1 = pa1[c];
        if constexpr (AMODE == 2) {
          v0.x += pb0[c].x; v0.y += pb0[c].y; v0.z += pb0[c].z; v0.w += pb0[c].w;
          v1.x += pb1[c].x; v1.y += pb1[c].y; v1.z += pb1[c].z; v1.w += pb1[c].w;
        }
        ushort tmp[8] = {f2bf(v0.x), f2bf(v0.y), f2bf(v0.z), f2bf(v0.w),
                         f2bf(v1.x), f2bf(v1.y), f2bf(v1.z), f2bf(v1.w)};
        *reinterpret_cast<short8*>(&Alds[row * 32 + scol]) =
            *reinterpret_cast<short8*>(tmp);
      }
    }
    __syncthreads();
    // prefetch next K-step's A while MFMA runs (T14 issue-early)
    if constexpr (AMODE != 0) {
      if (k0 + 32 < K) loadA(k0 + 32);
    }

    short8 af[4], bfr[4];
#pragma unroll
    for (int mi = 0; mi < 4; ++mi)
      af[mi] = *reinterpret_cast<const short8*>(&Alds[(wr + mi * 16 + lr) * 32 + lg * 8]);
#pragma unroll
    for (int ni = 0; ni < 4; ++ni)
      bfr[ni] = *reinterpret_cast<const short8*>(&Blds[(wc + ni * 16 + lr) * 32 + lg * 8]);
#pragma unroll
    for (int mi = 0; mi < 4; ++mi)
#pragma unroll
      for (int ni = 0; ni < 4; ++ni)
        acc[mi][ni] = __builtin_amdgcn_mfma_f32_16x16x32_bf16(af[mi], bfr[ni], acc[mi][ni], 0, 0, 0);
  }

#pragma unroll
  for (int mi = 0; mi < 4; ++mi)
#pragma unroll
    for (int ni = 0; ni < 4; ++ni) {
      int gn = n0 + wc + ni * 16 + lr;
      float bv = (OMODE == 7) ? (gn < 256 ? bias[gn] : bias2[gn - 256]) : bias[gn];
      f32x4 v = acc[mi][ni];
#pragma unroll
      for (int r = 0; r < 4; ++r) {
        int gm = m0 + wr + mi * 16 + lg * 4 + r;
        if (gm >= M) continue;
        float cv = v[r] + bv;
        if constexpr (OMODE == 0) {
          stv(&C[(size_t)gm * N + gn], cv);
        } else if constexpr (OMODE == 1) {
          cv += res[(size_t)gm * N + gn];
          stv(&C[(size_t)gm * N + gn], cv);
        } else if constexpr (OMODE == 2) {
          cv = fmaxf(cv, 0.f);
          stv(&C[(size_t)gm * N + gn], cv);
        } else if constexpr (OMODE == 4) {
          int q = gm >> 3, b = gm & 7;
          if (gn < 256) {
            int h = gn >> 5, d = gn & 31;
            ((ushort*)C)[(((size_t)b * 8 + h) * 1024 + q) * 32 + d] = f2bf(cv);
          } else {
            int gg = gn - 256, h = gg >> 5, d = gg & 31;
            ((ushort*)C2v)[(((size_t)b * 8 + h) * 960 + q) * 32 + d] = f2bf(cv);
          }
        } else if constexpr (OMODE == 5) {
          int q = gm >> 3, b = gm & 7, h = gn >> 5, d = gn & 31;
          ((ushort*)C)[(((size_t)b * 8 + h) * 960 + q) * 32 + d] = f2bf(cv);
        } else if constexpr (OMODE == 7) {
          if (gn < 256) ((float*)C)[(size_t)gm * 256 + gn] = cv;
          else          ((float*)C2v)[(size_t)gm * 128 + gn - 256] = cv;
        } else if constexpr (OMODE == 8) {
          ((ushort*)C)[((size_t)bz * TOT_ + gm) * 256 + gn] = f2bf(cv);
        }
      }
    }
}

// ---------------------------------------------------------------------------
// MFMA flash self-attention (verified structure + setprio).
// ---------------------------------------------------------------------------
__global__ __launch_bounds__(256) void attn_mfma(
    const ushort* __restrict__ Q, const ushort* __restrict__ Kt,
    const ushort* __restrict__ Vt, ushort* __restrict__ O) {
  const int qt = blockIdx.x, pr = blockIdx.y;
  const int b = pr >> 3, h = pr & 7;
  const int tid = threadIdx.x, w = tid >> 6, l = tid & 63;
  const int lr = l & 15, lg = l >> 4;
  const int qbase = qt * 128 + w * 32;
  const float SC = 0.17677669529663687f;

  __shared__ ushort Klds[64 * 32];
  __shared__ ushort Vlds[32 * 64];
  __shared__ ushort Plds[4 * 32 * 64];

  short8 qf[2];
#pragma unroll
  for (int nf = 0; nf < 2; ++nf) {
    int q = qbase + nf * 16 + lr;
    qf[nf] = *reinterpret_cast<const short8*>(&Q[((size_t)pr * 1024 + q) * 32 + lg * 8]);
  }
  f32x4 ot[2][2] = {};
  float mrow[2] = {-1e30f, -1e30f};
  float lsum[2] = {0.f, 0.f};

  for (int kt = 0; kt < 15; ++kt) {
    const int kv0 = kt * 64;
    __syncthreads();
    {
      int row = tid >> 2, s = tid & 3;
      short8 kv8 = *reinterpret_cast<const short8*>(
          &Kt[((size_t)pr * 960 + kv0 + row) * 32 + s * 8]);
      int s2 = s ^ ((row >> 1) & 3);
      *reinterpret_cast<short8*>(&Klds[row * 32 + s2 * 8]) = kv8;
      ushort tmp[8];
      *reinterpret_cast<short8*>(tmp) = *reinterpret_cast<const short8*>(
          &Vt[((size_t)pr * 960 + kv0 + row) * 32 + s * 8]);
      int slot = row >> 3;
#pragma unroll
      for (int j = 0; j < 8; ++j) {
        int d = s * 8 + j;
        Vlds[d * 64 + (slot ^ (d & 7)) * 8 + (row & 7)] = tmp[j];
      }
    }
    __syncthreads();

    short8 kf[4];
#pragma unroll
    for (int mf = 0; mf < 4; ++mf) {
      int row = mf * 16 + lr;
      int s2 = lg ^ ((row >> 1) & 3);
      kf[mf] = *reinterpret_cast<const short8*>(&Klds[row * 32 + s2 * 8]);
    }
    f32x4 sf[4][2];
    __builtin_amdgcn_s_setprio(1);
#pragma unroll
    for (int mf = 0; mf < 4; ++mf)
#pragma unroll
      for (int nf = 0; nf < 2; ++nf) {
        f32x4 z = {0.f, 0.f, 0.f, 0.f};
        sf[mf][nf] = __builtin_amdgcn_mfma_f32_16x16x32_bf16(kf[mf], qf[nf], z, 0, 0, 0);
      }
    __builtin_amdgcn_s_setprio(0);

#pragma unroll
    for (int nf = 0; nf < 2; ++nf) {
      float tm = -1e30f;
#pragma unroll
      for (int mf = 0; mf < 4; ++mf)
#pragma unroll
        for (int r = 0; r < 4; ++r) {
          float s = sf[mf][nf][r] * SC;
          int kv = kv0 + mf * 16 + lg * 4 + r;
          if (kv >= NQ_) s = -1e30f;
          sf[mf][nf][r] = s;
          tm = fmaxf(tm, s);
        }
      tm = fmaxf(tm, __shfl_xor(tm, 16));
      tm = fmaxf(tm, __shfl_xor(tm, 32));
      float mnew = fmaxf(mrow[nf], tm);
      float c = __expf(mrow[nf] - mnew);
      mrow[nf] = mnew;
      float ps = 0.f;
      int q_local = nf * 16 + lr;
#pragma unroll
      for (int mf = 0; mf < 4; ++mf) {
        ushort4 pk;
        float p0 = __expf(sf[mf][nf][0] - mnew);
        float p1 = __expf(sf[mf][nf][1] - mnew);
        float p2 = __expf(sf[mf][nf][2] - mnew);
        float p3 = __expf(sf[mf][nf][3] - mnew);
        ps += p0 + p1 + p2 + p3;
        pk.x = f2bf(p0); pk.y = f2bf(p1); pk.z = f2bf(p2); pk.w = f2bf(p3);
        int kvl = mf * 16 + lg * 4;
        int s3 = (kvl >> 3) ^ (q_local & 7);
        *reinterpret_cast<ushort4*>(
            &Plds[w * 2048 + q_local * 64 + s3 * 8 + (kvl & 7)]) = pk;
      }
      lsum[nf] = lsum[nf] * c + ps;
#pragma unroll
      for (int mf = 0; mf < 2; ++mf)
#pragma unroll
        for (int r = 0; r < 4; ++r) ot[mf][nf][r] *= c;
    }

#pragma unroll
    for (int ks = 0; ks < 2; ++ks) {
      short8 va[2], pb[2];
#pragma unroll
      for (int mf = 0; mf < 2; ++mf) {
        int d = mf * 16 + lr;
        int s3 = (ks * 4 + lg) ^ (d & 7);
        va[mf] = *reinterpret_cast<const short8*>(&Vlds[d * 64 + s3 * 8]);
      }
#pragma unroll
      for (int nf = 0; nf < 2; ++nf) {
        int q_local = nf * 16 + lr;
        int s3 = (ks * 4 + lg) ^ (q_local & 7);
        pb[nf] = *reinterpret_cast<const short8*>(&Plds[w * 2048 + q_local * 64 + s3 * 8]);
      }
      __builtin_amdgcn_s_setprio(1);
#pragma unroll
      for (int mf = 0; mf < 2; ++mf)
#pragma unroll
        for (int nf = 0; nf < 2; ++nf)
          ot[mf][nf] = __builtin_amdgcn_mfma_f32_16x16x32_bf16(va[mf], pb[nf], ot[mf][nf], 0, 0, 0);
      __builtin_amdgcn_s_setprio(0);
    }
  }

#pragma unroll
  for (int nf = 0; nf < 2; ++nf) {
    float ls = lsum[nf];
    ls += __shfl_xor(ls, 16);
    ls += __shfl_xor(ls, 32);
    float inv = 1.f / ls;
    int q = qbase + nf * 16 + lr;
    if (q < NQ_) {
#pragma unroll
      for (int mf = 0; mf < 2; ++mf) {
        ushort4 pk;
        pk.x = f2bf(ot[mf][nf][0] * inv); pk.y = f2bf(ot[mf][nf][1] * inv);
        pk.z = f2bf(ot[mf][nf][2] * inv); pk.w = f2bf(ot[mf][nf][3] * inv);
        int d0 = mf * 16 + lg * 4;
        *reinterpret_cast<ushort4*>(&O[((size_t)q * 8 + b) * 256 + h * 32 + d0]) = pk;
      }
    }
  }
}

// ---------------------------------------------------------------------------
// Multi-scale deformable sampling: 4 tokens/block, thread = (token, h, d/4).
// ---------------------------------------------------------------------------
__global__ __launch_bounds__(256) void deform_k(const ushort* __restrict__ val,
                                                const float* __restrict__ off,
                                                const float* __restrict__ awraw,
                                                const float* __restrict__ ref,
                                                ushort* __restrict__ out) {
  const int t0 = blockIdx.x * 4;
  const int tid = threadIdx.x;
  __shared__ float sx[4][128], sy[4][128], sw[4][128];
  const int LH[4] = {100, 50, 25, 13};
  const int LS[4] = {0, 10000, 12500, 13125};

  for (int e = tid; e < 512; e += 256) {
    int tt = e >> 7, lp = e & 127;
    int t = t0 + tt;
    int lvl = (lp >> 2) & 3;
    float ox = off[(size_t)t * 256 + lp * 2 + 0];
    float oy = off[(size_t)t * 256 + lp * 2 + 1];
    float rx = ref[((size_t)t * 4 + lvl) * 2 + 0];
    float ry = ref[((size_t)t * 4 + lvl) * 2 + 1];
    sx[tt][lp] = rx * (float)LH[lvl] + ox - 0.5f;
    sy[tt][lp] = ry * (float)LH[lvl] + oy - 0.5f;
    sw[tt][lp] = awraw[(size_t)t * 128 + lp];
  }
  __syncthreads();
  if (tid < 32) {
    int tt = tid >> 3, h = tid & 7;
    float* p = &sw[tt][h * 16];
    float mx = -1e30f;
#pragma unroll
    for (int k = 0; k < 16; ++k) mx = fmaxf(mx, p[k]);
    float v[16], s = 0.f;
#pragma unroll
    for (int k = 0; k < 16; ++k) { v[k] = __expf(p[k] - mx); s += v[k]; }
    float inv = 1.f / s;
#pragma unroll
    for (int k = 0; k < 16; ++k) p[k] = v[k] * inv;
  }
  __syncthreads();

  const int tt = tid >> 6, u = tid & 63;
  const int h = u >> 3, d0 = (u & 7) * 4;
  const int t = t0 + tt, b = t & 7;
  float a0 = 0.f, a1 = 0.f, a2 = 0.f, a3 = 0.f;

#pragma unroll
  for (int lvl = 0; lvl < 4; ++lvl) {
    const int Hl = LH[lvl], st = LS[lvl];
#pragma unroll
    for (int p = 0; p < 4; ++p) {
      int lp = (h * 4 + lvl) * 4 + p;
      float x = sx[tt][lp], y = sy[tt][lp], a = sw[tt][lp];
      float xf = floorf(x), yf = floorf(y);
      int x0 = (int)xf, y0 = (int)yf;
      float wx1 = x - xf, wx0 = 1.f - wx1;
      float wy1 = y - yf, wy0 = 1.f - wy1;
      float s0 = 0.f, s1 = 0.f, s2 = 0.f, s3 = 0.f;
#pragma unroll
      for (int cy = 0; cy < 2; ++cy)
#pragma unroll
        for (int cx = 0; cx < 2; ++cx) {
          int xi = x0 + cx, yi = y0 + cy;
          if (xi < 0 || xi >= Hl || yi < 0 || yi >= Hl) continue;
          ushort4 v4 = *reinterpret_cast<const ushort4*>(
              &val[((size_t)b * TOT_ + st + yi * Hl + xi) * 256 + h * 32 + d0]);
          float wgt = (cx ? wx1 : wx0) * (cy ? wy1 : wy0);
          s0 += wgt * bf2f(v4.x); s1 += wgt * bf2f(v4.y);
          s2 += wgt * bf2f(v4.z); s3 += wgt * bf2f(v4.w);
        }
      a0 += a * s0; a1 += a * s1; a2 += a * s2; a3 += a * s3;
    }
  }
  ushort4 o4; o4.x = f2bf(a0); o4.y = f2bf(a1); o4.z = f2bf(a2); o4.w = f2bf(a3);
  *reinterpret_cast<ushort4*>(&out[(size_t)t * 256 + h * 32 + d0]) = o4;
}

// ---------------------------------------------------------------------------
// LayerNorm rows of 256, one wave per row.
// MODE 0: fp32 out only. MODE 1: + bf16(x+pos) to aux. MODE 2: + bf16(x) aux.
// ---------------------------------------------------------------------------
template <int MODE>
__global__ __launch_bounds__(256) void ln_k(const float* __restrict__ z,
                                            const float* __restrict__ g,
                                            const float* __restrict__ be,
                                            float* __restrict__ out,
                                            const float* __restrict__ pos,
                                            ushort* __restrict__ aux, int rows) {
  const int wv = threadIdx.x >> 6, lane = threadIdx.x & 63;
  const int row = blockIdx.x * 4 + wv;
  if (row >= rows) return;
  float4 v = *reinterpret_cast<const float4*>(&z[(size_t)row * 256 + lane * 4]);
  float s = v.x + v.y + v.z + v.w;
#pragma unroll
  for (int o = 32; o; o >>= 1) s += __shfl_xor(s, o);
  float mean = s * (1.f / 256.f);
  float dx = v.x - mean, dy = v.y - mean, dz = v.z - mean, dw = v.w - mean;
  float vs = dx * dx + dy * dy + dz * dz + dw * dw;
#pragma unroll
  for (int o = 32; o; o >>= 1) vs += __shfl_xor(vs, o);
  float rstd = rsqrtf(vs * (1.f / 256.f) + 1e-5f);
  float4 gg = *reinterpret_cast<const float4*>(&g[lane * 4]);
  float4 bb = *reinterpret_cast<const float4*>(&be[lane * 4]);
  float4 r;
  r.x = dx * rstd * gg.x + bb.x;
  r.y = dy * rstd * gg.y + bb.y;
  r.z = dz * rstd * gg.z + bb.z;
  r.w = dw * rstd * gg.w + bb.w;
  *reinterpret_cast<float4*>(&out[(size_t)row * 256 + lane * 4]) = r;
  if constexpr (MODE == 1) {
    float4 pv = *reinterpret_cast<const float4*>(&pos[(size_t)row * 256 + lane * 4]);
    ushort4 a;
    a.x = f2bf(r.x + pv.x); a.y = f2bf(r.y + pv.y);
    a.z = f2bf(r.z + pv.z); a.w = f2bf(r.w + pv.w);
    *reinterpret_cast<ushort4*>(&aux[(size_t)row * 256 + lane * 4]) = a;
  } else if constexpr (MODE == 2) {
    ushort4 a;
    a.x = f2bf(r.x); a.y = f2bf(r.y); a.z = f2bf(r.z); a.w = f2bf(r.w);
    *reinterpret_cast<ushort4*>(&aux[(size_t)row * 256 + lane * 4]) = a;
  }
}

// ---------------------------------------------------------------------------
extern "C" void kernel_launch(void* const* d_in, const int* in_sizes, int n_in,
                              void* d_out, int out_size, void* d_ws, size_t ws_size,
                              hipStream_t stream) {
  const float* tgt    = (const float*)d_in[0];
  const float* pos    = (const float*)d_in[1];
  const float* refpts = (const float*)d_in[2];
  const float* memory = (const float*)d_in[3];
  const float* sa_in_b  = (const float*)d_in[7];
  const float* sa_out_b = (const float*)d_in[9];
  const float* norm1_g = (const float*)d_in[10];
  const float* norm1_b = (const float*)d_in[11];
  const float* norm2_g = (const float*)d_in[12];
  const float* norm2_b = (const float*)d_in[13];
  const float* norm3_g = (const float*)d_in[14];
  const float* norm3_b = (const float*)d_in[15];
  const float* samp_b = (const float*)d_in[17];
  const float* attw_b = (const float*)d_in[19];
  const float* val_b  = (const float*)d_in[21];
  const float* outp_b = (const float*)d_in[23];
  const float* lin1_b = (const float*)d_in[25];
  const float* lin2_b = (const float*)d_in[27];
  float* out = (float*)d_out;

  char* ws = (char*)d_ws;
  ushort* wbf  = (ushort*)(ws + 0);            // bf16 weight arena
  ushort* valb = (ushort*)(ws + 2097152);      // [b][13294][256] bf16
  char*   S    = ws + 56549376;                // 27,262,976 B scratch union
  float*  bufC = (float*)(ws + 83812352);      // 7,372,800
  float*  bufD = (float*)(ws + 91185152);      // 7,372,800

  // weight arena element offsets (x256 cols)
  ushort* sa_in_bf  = wbf + 0;        // 512 rows
  ushort* sa_out_bf = wbf + 131072;   // 256
  ushort* sampw_bf  = wbf + 196608;   // 384 (samp 256 + attw 128)
  ushort* val_bf    = wbf + 294912;   // 256
  ushort* outp_bf   = wbf + 360448;   // 256
  ushort* lin1_bf   = wbf + 425984;   // 1024
  ushort* lin2_bf   = wbf + 688128;   // 256 x 1024

  // scratch union (phase-ordered; all overlaps stream-safe)
  ushort* Qatt = (ushort*)(S + 0);         // 4,194,304
  ushort* Katt = (ushort*)(S + 4194304);   // 3,932,160
  ushort* Vatt = (ushort*)(S + 8126464);   // 3,932,160
  ushort* O_bf = (ushort*)(S + 12058624);  // 3,686,400 (ends 15,745,024)
  ushort* q2bf = (ushort*)(S + 0);         // 3,686,400 (Qatt dead after attn)
  float*  offs = (float*)(S + 3686400);    // 7,372,800
  float*  awb  = (float*)(S + 11059200);   // 3,686,400 (O_bf dead after outproj)
  ushort* dbuf = (ushort*)(S + 15745024);  // 3,686,400
  ushort* t2bf = (ushort*)(S + 0);         // 3,686,400 (q2bf dead after offs)
  ushort* hid  = (ushort*)(S + 3686400);   // 14,745,600 (offs/awb dead)

  // 1. weights -> bf16 arena
  cvtw_k<<<928, 256, 0, stream>>>(wbf, (const float*)d_in[6], (const float*)d_in[8],
      (const float*)d_in[16], (const float*)d_in[18], (const float*)d_in[20],
      (const float*)d_in[22], (const float*)d_in[24], (const float*)d_in[26]);

  // 2. value projection: s-major A rows (s*8+b), b-major coalesced writes
  g2<128, 3, 8, ushort><<<dim3(2, 104, 8), 256, 0, stream>>>(
      memory, nullptr, val_bf, val_b, nullptr, nullptr, valb, nullptr, TOT_, 256, 256);

  // 3. QK projection (A = tgt + pos) and V projection (A = tgt)
  g2<256, 2, 4, ushort><<<dim3(2, 57), 512, 0, stream>>>(
      tgt, pos, sa_in_bf, sa_in_b, nullptr, nullptr, Qatt, Katt, NT_, 512, 256);
  g2<128, 1, 5, ushort><<<dim3(2, 57), 256, 0, stream>>>(
      tgt, nullptr, sa_in_bf + 512 * 256, sa_in_b + 512, nullptr, nullptr,
      Vatt, nullptr, NT_, 256, 256);

  // 4. attention
  attn_mfma<<<dim3(8, 64), 256, 0, stream>>>(Qatt, Katt, Vatt, O_bf);

  // 5. out projection + residual(tgt) -> bufC ; LN2 -> bufD + bf16(tgt1+pos)
  g2<128, 0, 1, float><<<dim3(2, 57), 256, 0, stream>>>(
      O_bf, nullptr, sa_out_bf, sa_out_b, nullptr, tgt, bufC, nullptr, NT_, 256, 256);
  ln_k<1><<<1800, 256, 0, stream>>>(bufC, norm2_g, norm2_b, bufD, pos, q2bf, NT_);

  // 6. fused offs+attw GEMM (A = bf16 q2, gload_lds path)
  g2<128, 0, 7, float><<<dim3(3, 57), 256, 0, stream>>>(
      q2bf, nullptr, sampw_bf, samp_b, attw_b, nullptr, offs, awb, NT_, 384, 256);

  // 7. deformable sampling (includes aw softmax) -> dbuf bf16
  deform_k<<<1800, 256, 0, stream>>>(valb, offs, awb, refpts, dbuf);

  // 8. output projection + residual(tgt1) -> bufC ; LN1 -> bufD + bf16(tgt2)
  g2<128, 0, 1, float><<<dim3(2, 57), 256, 0, stream>>>(
      dbuf, nullptr, outp_bf, outp_b, nullptr, bufD, bufC, nullptr, NT_, 256, 256);
  ln_k<2><<<1800, 256, 0, stream>>>(bufC, norm1_g, norm1_b, bufD, nullptr, t2bf, NT_);

  // 9. FFN: lin1 (bf16 A, ReLU) ; lin2 (+res) ; LN3 -> out
  g2<256, 0, 2, ushort><<<dim3(4, 57), 512, 0, stream>>>(
      t2bf, nullptr, lin1_bf, lin1_b, nullptr, nullptr, hid, nullptr, NT_, 1024, 256);
  g2<128, 0, 1, float><<<dim3(2, 57), 256, 0, stream>>>(
      hid, nullptr, lin2_bf, lin2_b, nullptr, bufD, bufC, nullptr, NT_, 256, 1024);
  ln_k<0><<<1800, 256, 0, stream>>>(bufC, norm3_g, norm3_b, out, nullptr, nullptr, NT_);
}